// Round 1
// baseline (6809.225 us; speedup 1.0000x reference)
//
#include <hip/hip_runtime.h>
#include <hip/hip_bf16.h>

// ---------------------------------------------------------------------------
// VisualContrastAttention on MI355X (gfx950)
// B=32, N=1024 (32x32), C=768, heads=12, hd=64, pool 8x8=64 tokens
// Pipeline:
//   K0  cast x/Wqkv/Wproj f32->bf16
//   K1  qkv GEMM (bf16 MFMA 16x16x32), split-store q/k/v as [b,h,n,d] bf16
//   K2  depthwise conv3x3+GELU+avgpool4x4 + gq + t_pos/t_neg
//   K3  stage-1 attention (64 pooled tokens x 1024 kv), online softmax,
//       v_contrast = rmsnorm(vhp - lam1*vhn)*0.5
//   K4  stage-2 attention (1024 q x 64 tokens), out_patch bf16 [B,N,768]
//   K5  proj GEMM (bf16 MFMA) + bias -> f32 d_out
// ---------------------------------------------------------------------------

typedef __attribute__((ext_vector_type(8))) short short8;
typedef __attribute__((ext_vector_type(4))) float f32x4;

#define DEV static __device__ __forceinline__

DEV unsigned short f2bf(float f) {
  unsigned int b; __builtin_memcpy(&b, &f, 4);
  unsigned int r = (b + 0x7FFFu + ((b >> 16) & 1u)) >> 16;
  return (unsigned short)r;
}
DEV float bf2f(unsigned short u) {
  unsigned int b = ((unsigned int)u) << 16;
  float f; __builtin_memcpy(&f, &b, 4);
  return f;
}
DEV float bflo(unsigned int w) { unsigned int b = w << 16; float f; __builtin_memcpy(&f, &b, 4); return f; }
DEV float bfhi(unsigned int w) { unsigned int b = w & 0xffff0000u; float f; __builtin_memcpy(&f, &b, 4); return f; }

// ---- workspace layout (bytes) ---------------------------------------------
constexpr size_t SZ_QKV = (size_t)32 * 12 * 1024 * 64 * 2;   // 50331648 (bf16)
constexpr size_t OFF_Q  = 0;
constexpr size_t OFF_K  = OFF_Q + SZ_QKV;
constexpr size_t OFF_V  = OFF_K + SZ_QKV;
constexpr size_t OFF_TP = OFF_V + SZ_QKV;                    // f32 384*4096*4
constexpr size_t OFF_TN = OFF_TP + 6291456;
constexpr size_t OFF_VC = OFF_TN + 6291456;
constexpr size_t OFF_OP = OFF_VC + 6291456;                  // bf16 32768*768
constexpr size_t OFF_XB = OFF_OP + 50331648;                 // bf16 x
constexpr size_t OFF_WQ = OFF_XB + 50331648;                 // bf16 Wqkv
constexpr size_t OFF_WP = OFF_WQ + 3538944;                  // bf16 Wproj
// total = 275251200 bytes (~263 MB)

// ---- K0: f32 -> bf16 cast --------------------------------------------------
__global__ __launch_bounds__(256) void cast_kernel(const float* __restrict__ src,
                                                   unsigned short* __restrict__ dst, int n4) {
  int i = blockIdx.x * 256 + threadIdx.x;
  if (i >= n4) return;
  float4 v = reinterpret_cast<const float4*>(src)[i];
  ushort4 o;
  o.x = f2bf(v.x); o.y = f2bf(v.y); o.z = f2bf(v.z); o.w = f2bf(v.w);
  reinterpret_cast<ushort4*>(dst)[i] = o;
}

// ---- K1: qkv GEMM, M=32768 N=2304 K=768, split store ----------------------
// 256 thr = 4 waves (2x2), block tile 128x128, BK=32, LDS pad row 40 bf16.
__global__ __launch_bounds__(256) void gemm_qkv_kernel(const unsigned short* __restrict__ A,
    const unsigned short* __restrict__ Bm, unsigned short* __restrict__ q,
    unsigned short* __restrict__ k, unsigned short* __restrict__ v) {
  __shared__ unsigned short As[128 * 40];
  __shared__ unsigned short Bs[128 * 40];
  const int t = threadIdx.x;
  const int lane = t & 63;
  const int w = t >> 6;
  const int wm = w >> 1, wn = w & 1;
  const int row0 = blockIdx.y * 128;
  const int col0 = blockIdx.x * 128;
  f32x4 acc[4][4];
#pragma unroll
  for (int i = 0; i < 4; ++i)
#pragma unroll
    for (int j = 0; j < 4; ++j) acc[i][j] = (f32x4){0.f, 0.f, 0.f, 0.f};
  const int mrow = lane & 15;
  const int kr = (lane >> 4) << 3;   // 0,8,16,24
  for (int k0 = 0; k0 < 768; k0 += 32) {
    __syncthreads();
    for (int L = t; L < 512; L += 256) {
      const int r = L >> 2, c8 = (L & 3) << 3;
      *reinterpret_cast<short8*>(As + r * 40 + c8) =
          *reinterpret_cast<const short8*>(A + (size_t)(row0 + r) * 768 + k0 + c8);
      *reinterpret_cast<short8*>(Bs + r * 40 + c8) =
          *reinterpret_cast<const short8*>(Bm + (size_t)(col0 + r) * 768 + k0 + c8);
    }
    __syncthreads();
    short8 af[4], bfv[4];
#pragma unroll
    for (int mt = 0; mt < 4; ++mt)
      af[mt] = *reinterpret_cast<const short8*>(As + (wm * 64 + mt * 16 + mrow) * 40 + kr);
#pragma unroll
    for (int nt = 0; nt < 4; ++nt)
      bfv[nt] = *reinterpret_cast<const short8*>(Bs + (wn * 64 + nt * 16 + mrow) * 40 + kr);
#pragma unroll
    for (int mt = 0; mt < 4; ++mt)
#pragma unroll
      for (int nt = 0; nt < 4; ++nt)
        acc[mt][nt] = __builtin_amdgcn_mfma_f32_16x16x32_bf16(af[mt], bfv[nt], acc[mt][nt], 0, 0, 0);
  }
  const int s_ = col0 / 768;   // tile never crosses q/k/v boundary (768%128==0)
  unsigned short* dst = (s_ == 0) ? q : ((s_ == 1) ? k : v);
#pragma unroll
  for (int nt = 0; nt < 4; ++nt) {
    const int colin = wn * 64 + nt * 16 + mrow;          // 0..127
    const int head = ((col0 % 768) + colin) >> 6;
    const int d = colin & 63;
#pragma unroll
    for (int mt = 0; mt < 4; ++mt) {
#pragma unroll
      for (int r = 0; r < 4; ++r) {
        const int row = row0 + wm * 64 + mt * 16 + ((lane >> 4) << 2) + r;
        const int b = row >> 10, n = row & 1023;
        dst[(((size_t)b * 12 + head) * 1024 + n) * 64 + d] = f2bf(acc[mt][nt][r]);
      }
    }
  }
}

// ---- K2: conv3x3 depthwise + GELU + pool + gq + t_pos/t_neg ---------------
__global__ __launch_bounds__(256) void conv_pool_kernel(const unsigned short* __restrict__ qg,
    const float* __restrict__ conv_w, const float* __restrict__ Wpos,
    const float* __restrict__ Wneg, float* __restrict__ t_pos, float* __restrict__ t_neg) {
  const int bh = blockIdx.x;               // 0..383
  const unsigned short* qp = qg + (size_t)bh * 1024 * 64;
  __shared__ float pool_s[64][64];
  __shared__ float red[4][64];
  __shared__ float gq_s[64], ep_s[64], en_s[64];
  const int t = threadIdx.x;
  const int d = t & 63;
  { // gq = mean over n of raw q
    const int part = t >> 6;
    float s = 0.f;
    for (int i = 0; i < 256; ++i) s += bf2f(qp[(size_t)(part * 256 + i) * 64 + d]);
    red[part][d] = s;
  }
  __syncthreads();
  if (t < 64) gq_s[t] = (red[0][t] + red[1][t] + red[2][t] + red[3][t]) * (1.0f / 1024.0f);
  // conv + gelu + 4x4 mean pool; thread owns (m,d) cells
  float cw[9];
#pragma unroll
  for (int j = 0; j < 9; ++j) cw[j] = conv_w[d * 9 + j];
  for (int i = 0; i < 16; ++i) {
    const int task = i * 256 + t;
    const int m = task >> 6;               // pooled token 0..63
    const int py = m >> 3, px = m & 7;
    float sum = 0.f;
    for (int iy = 0; iy < 4; ++iy) {
      const int y = py * 4 + iy;
      for (int ix = 0; ix < 4; ++ix) {
        const int x = px * 4 + ix;
        float acc = 0.f;
#pragma unroll
        for (int dy = -1; dy <= 1; ++dy) {
          const int yy = y + dy;
          if (yy < 0 || yy > 31) continue;
#pragma unroll
          for (int dx = -1; dx <= 1; ++dx) {
            const int xx = x + dx;
            if (xx < 0 || xx > 31) continue;
            acc += bf2f(qp[(size_t)(yy * 32 + xx) * 64 + d]) * cw[(dy + 1) * 3 + (dx + 1)];
          }
        }
        const float g = 0.5f * acc * (1.0f + erff(acc * 0.70710678118654752440f));
        sum += g;
      }
    }
    pool_s[m][d] = sum * (1.0f / 16.0f);
  }
  __syncthreads();
  if (t < 128) {
    const int d2 = t & 63;
    const float* Wm = (t < 64) ? Wpos : Wneg;
    float e = 0.f;
    for (int dd = 0; dd < 64; ++dd) e += gq_s[dd] * Wm[d2 * 64 + dd];
    (t < 64 ? ep_s : en_s)[d2] = e;
  }
  __syncthreads();
  for (int i = 0; i < 16; ++i) {
    const int task = i * 256 + t;
    const int m = task >> 6, dd = task & 63;
    const float base = pool_s[m][dd];
    t_pos[(size_t)bh * 4096 + task] = base + ep_s[dd];
    t_neg[(size_t)bh * 4096 + task] = base + en_s[dd];
  }
}

// ---- K3: stage-1 attention + contrast + rmsnorm ---------------------------
// block = (b,h); 256 thr; thread = (row m = t>>2, quarter qq = t&3)
__global__ __launch_bounds__(256) void stage1_kernel(const unsigned short* __restrict__ kg,
    const unsigned short* __restrict__ vg, const float* __restrict__ t_pos,
    const float* __restrict__ t_neg, const float* __restrict__ lam1p,
    const float* __restrict__ norm1_w, float* __restrict__ v_contrast) {
  const int bh = blockIdx.x;
  __shared__ unsigned short tp[64 * 72], tn[64 * 72];
  __shared__ unsigned short ks[64 * 72], vs[64 * 72];
  __shared__ float S[64][68];
  const int t = threadIdx.x;
  const int mrow = t >> 2, qq = t & 3;
  for (int L = t; L < 4096; L += 256) {
    const int m = L >> 6, dd = L & 63;
    tp[m * 72 + dd] = f2bf(t_pos[(size_t)bh * 4096 + L]);
    tn[m * 72 + dd] = f2bf(t_neg[(size_t)bh * 4096 + L]);
  }
  float m1 = -1e30f, l1 = 0.f, m2 = -1e30f, l2 = 0.f;
  float acc1[16], acc2[16];
#pragma unroll
  for (int i = 0; i < 16; ++i) { acc1[i] = 0.f; acc2[i] = 0.f; }
  const size_t base = (size_t)bh * 65536;

  auto pass = [&](const unsigned short* tmat, float& rm, float& rl, float* accv) {
    float sacc[16];
#pragma unroll
    for (int j = 0; j < 16; ++j) sacc[j] = 0.f;
#pragma unroll
    for (int db = 0; db < 8; ++db) {
      const uint4 tv = *reinterpret_cast<const uint4*>(tmat + mrow * 72 + db * 8);
      const float ta0 = bflo(tv.x), ta1 = bfhi(tv.x), ta2 = bflo(tv.y), ta3 = bfhi(tv.y);
      const float ta4 = bflo(tv.z), ta5 = bfhi(tv.z), ta6 = bflo(tv.w), ta7 = bfhi(tv.w);
#pragma unroll
      for (int j = 0; j < 16; ++j) {
        const uint4 kv = *reinterpret_cast<const uint4*>(ks + (qq * 16 + j) * 72 + db * 8);
        sacc[j] += ta0 * bflo(kv.x) + ta1 * bfhi(kv.x) + ta2 * bflo(kv.y) + ta3 * bfhi(kv.y)
                 + ta4 * bflo(kv.z) + ta5 * bfhi(kv.z) + ta6 * bflo(kv.w) + ta7 * bfhi(kv.w);
      }
    }
    float lmax = -1e30f;
#pragma unroll
    for (int j = 0; j < 16; ++j) { sacc[j] *= 0.125f; lmax = fmaxf(lmax, sacc[j]); }
    lmax = fmaxf(lmax, __shfl_xor(lmax, 1));
    lmax = fmaxf(lmax, __shfl_xor(lmax, 2));
    const float newm = fmaxf(rm, lmax);
    const float alpha = __expf(rm - newm);
    float psum = 0.f;
#pragma unroll
    for (int j = 0; j < 16; ++j) {
      const float p = __expf(sacc[j] - newm);
      S[mrow][qq * 16 + j] = p;
      psum += p;
    }
    psum += __shfl_xor(psum, 1);
    psum += __shfl_xor(psum, 2);
    rl = rl * alpha + psum;
    rm = newm;
#pragma unroll
    for (int dd = 0; dd < 16; ++dd) accv[dd] *= alpha;
    for (int n = 0; n < 64; ++n) {
      const float p = S[mrow][n];   // same-wave producers (4 lanes per row)
      const uint4 v0 = *reinterpret_cast<const uint4*>(vs + n * 72 + qq * 16);
      const uint4 v1 = *reinterpret_cast<const uint4*>(vs + n * 72 + qq * 16 + 8);
      accv[0] += p * bflo(v0.x); accv[1] += p * bfhi(v0.x);
      accv[2] += p * bflo(v0.y); accv[3] += p * bfhi(v0.y);
      accv[4] += p * bflo(v0.z); accv[5] += p * bfhi(v0.z);
      accv[6] += p * bflo(v0.w); accv[7] += p * bfhi(v0.w);
      accv[8] += p * bflo(v1.x); accv[9] += p * bfhi(v1.x);
      accv[10] += p * bflo(v1.y); accv[11] += p * bfhi(v1.y);
      accv[12] += p * bflo(v1.z); accv[13] += p * bfhi(v1.z);
      accv[14] += p * bflo(v1.w); accv[15] += p * bfhi(v1.w);
    }
  };

  for (int n0 = 0; n0 < 1024; n0 += 64) {
    __syncthreads();
    for (int L = t; L < 512; L += 256) {
      const int r = L >> 3, c = (L & 7) << 3;
      *reinterpret_cast<short8*>(ks + r * 72 + c) =
          *reinterpret_cast<const short8*>(kg + base + (size_t)(n0 + r) * 64 + c);
      *reinterpret_cast<short8*>(vs + r * 72 + c) =
          *reinterpret_cast<const short8*>(vg + base + (size_t)(n0 + r) * 64 + c);
    }
    __syncthreads();
    pass(tp, m1, l1, acc1);
    pass(tn, m2, l2, acc2);
  }
  const float lam1 = lam1p[0];
  const float inv1 = 1.f / l1, inv2 = 1.f / l2;
  float diff[16];
  float ss = 0.f;
#pragma unroll
  for (int i = 0; i < 16; ++i) {
    diff[i] = acc1[i] * inv1 - lam1 * (acc2[i] * inv2);
    ss += diff[i] * diff[i];
  }
  ss += __shfl_xor(ss, 1);
  ss += __shfl_xor(ss, 2);
  const float rms = sqrtf(ss) * 0.125f;     // /sqrt(64)
  const float sc = 0.5f / (rms + 1e-6f);    // *(1-LAM1_INIT)
#pragma unroll
  for (int i = 0; i < 16; ++i)
    v_contrast[(size_t)bh * 4096 + mrow * 64 + qq * 16 + i] = diff[i] * sc * norm1_w[qq * 16 + i];
}

// ---- K4: stage-2 attention + rmsnorm -> out_patch bf16 [B,N,768] ----------
__global__ __launch_bounds__(256) void stage2_kernel(const unsigned short* __restrict__ qg,
    const float* __restrict__ t_pos, const float* __restrict__ t_neg,
    const float* __restrict__ v_contrast, const float* __restrict__ lam2p,
    const float* __restrict__ norm2_w, unsigned short* __restrict__ outp) {
  const int bh = blockIdx.x;
  const int r0 = blockIdx.y * 64;
  __shared__ unsigned short tp[64 * 72], tn[64 * 72], qs[64 * 72];
  __shared__ float vcs[64][68];
  __shared__ float S[64][68];
  const int t = threadIdx.x;
  for (int L = t; L < 4096; L += 256) {
    const int m = L >> 6, dd = L & 63;
    tp[m * 72 + dd] = f2bf(t_pos[(size_t)bh * 4096 + L]);
    tn[m * 72 + dd] = f2bf(t_neg[(size_t)bh * 4096 + L]);
    vcs[m][dd] = v_contrast[(size_t)bh * 4096 + L];
  }
  for (int L = t; L < 512; L += 256) {
    const int r = L >> 3, c = (L & 7) << 3;
    *reinterpret_cast<short8*>(qs + r * 72 + c) =
        *reinterpret_cast<const short8*>(qg + (size_t)bh * 65536 + (size_t)(r0 + r) * 64 + c);
  }
  __syncthreads();
  const int rr = t >> 2, qq = t & 3;
  float o1[16], o2[16];
#pragma unroll
  for (int i = 0; i < 16; ++i) { o1[i] = 0.f; o2[i] = 0.f; }

  auto pass = [&](const unsigned short* tmat, float* ov) {
    float sacc[16];
#pragma unroll
    for (int j = 0; j < 16; ++j) sacc[j] = 0.f;
#pragma unroll
    for (int db = 0; db < 8; ++db) {
      const uint4 qv = *reinterpret_cast<const uint4*>(qs + rr * 72 + db * 8);
      const float qa0 = bflo(qv.x), qa1 = bfhi(qv.x), qa2 = bflo(qv.y), qa3 = bfhi(qv.y);
      const float qa4 = bflo(qv.z), qa5 = bfhi(qv.z), qa6 = bflo(qv.w), qa7 = bfhi(qv.w);
#pragma unroll
      for (int j = 0; j < 16; ++j) {
        const uint4 tv = *reinterpret_cast<const uint4*>(tmat + (qq * 16 + j) * 72 + db * 8);
        sacc[j] += qa0 * bflo(tv.x) + qa1 * bfhi(tv.x) + qa2 * bflo(tv.y) + qa3 * bfhi(tv.y)
                 + qa4 * bflo(tv.z) + qa5 * bfhi(tv.z) + qa6 * bflo(tv.w) + qa7 * bfhi(tv.w);
      }
    }
    float lmax = -1e30f;
#pragma unroll
    for (int j = 0; j < 16; ++j) { sacc[j] *= 0.125f; lmax = fmaxf(lmax, sacc[j]); }
    lmax = fmaxf(lmax, __shfl_xor(lmax, 1));
    lmax = fmaxf(lmax, __shfl_xor(lmax, 2));
    float psum = 0.f;
#pragma unroll
    for (int j = 0; j < 16; ++j) { sacc[j] = __expf(sacc[j] - lmax); psum += sacc[j]; }
    psum += __shfl_xor(psum, 1);
    psum += __shfl_xor(psum, 2);
    const float winv = 1.f / psum;
#pragma unroll
    for (int j = 0; j < 16; ++j) S[rr][qq * 16 + j] = sacc[j] * winv;
    for (int m = 0; m < 64; ++m) {
      const float wgt = S[rr][m];
      const float4 a0 = *reinterpret_cast<const float4*>(&vcs[m][qq * 16]);
      const float4 a1 = *reinterpret_cast<const float4*>(&vcs[m][qq * 16 + 4]);
      const float4 a2 = *reinterpret_cast<const float4*>(&vcs[m][qq * 16 + 8]);
      const float4 a3 = *reinterpret_cast<const float4*>(&vcs[m][qq * 16 + 12]);
      ov[0] += wgt * a0.x; ov[1] += wgt * a0.y; ov[2] += wgt * a0.z; ov[3] += wgt * a0.w;
      ov[4] += wgt * a1.x; ov[5] += wgt * a1.y; ov[6] += wgt * a1.z; ov[7] += wgt * a1.w;
      ov[8] += wgt * a2.x; ov[9] += wgt * a2.y; ov[10] += wgt * a2.z; ov[11] += wgt * a2.w;
      ov[12] += wgt * a3.x; ov[13] += wgt * a3.y; ov[14] += wgt * a3.z; ov[15] += wgt * a3.w;
    }
  };
  pass(tp, o1);
  pass(tn, o2);
  const float lam2 = lam2p[0];
  float od[16];
  float ss = 0.f;
#pragma unroll
  for (int i = 0; i < 16; ++i) {
    od[i] = o1[i] - lam2 * o2[i];
    ss += od[i] * od[i];
  }
  ss += __shfl_xor(ss, 1);
  ss += __shfl_xor(ss, 2);
  const float rms = sqrtf(ss) * 0.125f;
  const float sc = 0.5f / (rms + 1e-6f);
  const int b = bh / 12, head = bh % 12, n = r0 + rr;
  const size_t obase = ((size_t)b * 1024 + n) * 768 + head * 64 + qq * 16;
#pragma unroll
  for (int i = 0; i < 16; ++i)
    outp[obase + i] = f2bf(od[i] * sc * norm2_w[qq * 16 + i]);
}

// ---- K5: projection GEMM, M=32768 N=768 K=768, +bias, f32 out -------------
__global__ __launch_bounds__(256) void gemm_proj_kernel(const unsigned short* __restrict__ A,
    const unsigned short* __restrict__ Bm, const float* __restrict__ bias,
    float* __restrict__ out) {
  __shared__ unsigned short As[128 * 40];
  __shared__ unsigned short Bs[128 * 40];
  const int t = threadIdx.x;
  const int lane = t & 63;
  const int w = t >> 6;
  const int wm = w >> 1, wn = w & 1;
  const int row0 = blockIdx.y * 128;
  const int col0 = blockIdx.x * 128;
  f32x4 acc[4][4];
#pragma unroll
  for (int i = 0; i < 4; ++i)
#pragma unroll
    for (int j = 0; j < 4; ++j) acc[i][j] = (f32x4){0.f, 0.f, 0.f, 0.f};
  const int mrow = lane & 15;
  const int kr = (lane >> 4) << 3;
  for (int k0 = 0; k0 < 768; k0 += 32) {
    __syncthreads();
    for (int L = t; L < 512; L += 256) {
      const int r = L >> 2, c8 = (L & 3) << 3;
      *reinterpret_cast<short8*>(As + r * 40 + c8) =
          *reinterpret_cast<const short8*>(A + (size_t)(row0 + r) * 768 + k0 + c8);
      *reinterpret_cast<short8*>(Bs + r * 40 + c8) =
          *reinterpret_cast<const short8*>(Bm + (size_t)(col0 + r) * 768 + k0 + c8);
    }
    __syncthreads();
    short8 af[4], bfv[4];
#pragma unroll
    for (int mt = 0; mt < 4; ++mt)
      af[mt] = *reinterpret_cast<const short8*>(As + (wm * 64 + mt * 16 + mrow) * 40 + kr);
#pragma unroll
    for (int nt = 0; nt < 4; ++nt)
      bfv[nt] = *reinterpret_cast<const short8*>(Bs + (wn * 64 + nt * 16 + mrow) * 40 + kr);
#pragma unroll
    for (int mt = 0; mt < 4; ++mt)
#pragma unroll
      for (int nt = 0; nt < 4; ++nt)
        acc[mt][nt] = __builtin_amdgcn_mfma_f32_16x16x32_bf16(af[mt], bfv[nt], acc[mt][nt], 0, 0, 0);
  }
#pragma unroll
  for (int nt = 0; nt < 4; ++nt) {
    const int col = col0 + wn * 64 + nt * 16 + mrow;
    const float bv = bias[col];
#pragma unroll
    for (int mt = 0; mt < 4; ++mt)
#pragma unroll
      for (int r = 0; r < 4; ++r) {
        const int row = row0 + wm * 64 + mt * 16 + ((lane >> 4) << 2) + r;
        out[(size_t)row * 768 + col] = acc[mt][nt][r] + bv;
      }
  }
}

// ---------------------------------------------------------------------------
extern "C" void kernel_launch(void* const* d_in, const int* in_sizes, int n_in,
                              void* d_out, int out_size, void* d_ws, size_t ws_size,
                              hipStream_t stream) {
  (void)in_sizes; (void)n_in; (void)out_size; (void)ws_size;
  const float* x       = (const float*)d_in[0];
  const float* Wqkv    = (const float*)d_in[1];
  const float* Wproj   = (const float*)d_in[2];
  const float* bproj   = (const float*)d_in[3];
  const float* Wpos    = (const float*)d_in[4];
  const float* Wneg    = (const float*)d_in[5];
  const float* conv_w  = (const float*)d_in[6];
  const float* lam1    = (const float*)d_in[7];
  const float* lam2    = (const float*)d_in[8];
  const float* norm1_w = (const float*)d_in[9];
  const float* norm2_w = (const float*)d_in[10];
  float* out = (float*)d_out;
  char* ws = (char*)d_ws;
  unsigned short* qb  = (unsigned short*)(ws + OFF_Q);
  unsigned short* kb  = (unsigned short*)(ws + OFF_K);
  unsigned short* vb  = (unsigned short*)(ws + OFF_V);
  float* tposb        = (float*)(ws + OFF_TP);
  float* tnegb        = (float*)(ws + OFF_TN);
  float* vcb          = (float*)(ws + OFF_VC);
  unsigned short* opb = (unsigned short*)(ws + OFF_OP);
  unsigned short* xb  = (unsigned short*)(ws + OFF_XB);
  unsigned short* wqb = (unsigned short*)(ws + OFF_WQ);
  unsigned short* wpb = (unsigned short*)(ws + OFF_WP);

  cast_kernel<<<dim3(6291456 / 256), dim3(256), 0, stream>>>(x, xb, 6291456);
  cast_kernel<<<dim3(442368 / 256), dim3(256), 0, stream>>>(Wqkv, wqb, 442368);
  cast_kernel<<<dim3(147456 / 256), dim3(256), 0, stream>>>(Wproj, wpb, 147456);
  gemm_qkv_kernel<<<dim3(18, 256), dim3(256), 0, stream>>>(xb, wqb, qb, kb, vb);
  conv_pool_kernel<<<dim3(384), dim3(256), 0, stream>>>(qb, conv_w, Wpos, Wneg, tposb, tnegb);
  stage1_kernel<<<dim3(384), dim3(256), 0, stream>>>(kb, vb, tposb, tnegb, lam1, norm1_w, vcb);
  stage2_kernel<<<dim3(384, 16), dim3(256), 0, stream>>>(qb, tposb, tnegb, vcb, lam2, norm2_w, opb);
  gemm_proj_kernel<<<dim3(6, 256), dim3(256), 0, stream>>>(opb, wpb, bproj, out);
}

// Round 2
// 661.064 us; speedup vs baseline: 10.3004x; 10.3004x over previous
//
#include <hip/hip_runtime.h>
#include <hip/hip_bf16.h>

// ---------------------------------------------------------------------------
// VisualContrastAttention on MI355X (gfx950)
// B=32, N=1024 (32x32), C=768, heads=12, hd=64, pool 8x8=64 tokens
// Pipeline:
//   K0  cast x/Wqkv/Wproj f32->bf16
//   K1  qkv GEMM (bf16 MFMA 16x16x32); q,k stored [b,h,n,d]; V stored
//       TRANSPOSED vt[b,h,d,n] (packed ushort4 along n) for stage1 PV
//   K2  depthwise conv3x3+GELU+avgpool + gq -> t_pos/t_neg (bf16)
//   K3  stage-1: swapped-QK^T MFMA flash (64 tok x 1024 kv, online softmax),
//       PV via mfma_16x16x16bf16_1k (P regs feed A-frag directly),
//       writes v_contrast TRANSPOSED vct[bh][d][m] f32
//   K4  stage-2: same structure (1024 q x 64 tok), out_patch bf16
//   K5  proj GEMM (bf16 MFMA) + bias -> f32 d_out
// ---------------------------------------------------------------------------

typedef __attribute__((ext_vector_type(8))) short short8;
typedef __attribute__((ext_vector_type(4))) short bf16x4;
typedef __attribute__((ext_vector_type(4))) float f32x4;

#define DEV static __device__ __forceinline__

DEV unsigned short f2bf(float f) {
  unsigned int b; __builtin_memcpy(&b, &f, 4);
  unsigned int r = (b + 0x7FFFu + ((b >> 16) & 1u)) >> 16;
  return (unsigned short)r;
}
DEV float bf2f(unsigned short u) {
  unsigned int b = ((unsigned int)u) << 16;
  float f; __builtin_memcpy(&f, &b, 4);
  return f;
}

// ---- workspace layout (bytes) ---------------------------------------------
constexpr size_t SZ_QKV = (size_t)32 * 12 * 1024 * 64 * 2;   // 50331648 bf16
constexpr size_t OFF_Q   = 0;
constexpr size_t OFF_K   = OFF_Q + SZ_QKV;                    //  50331648
constexpr size_t OFF_VT  = OFF_K + SZ_QKV;                    // 100663296  vt[bh][d][n] bf16
constexpr size_t OFF_TPB = OFF_VT + SZ_QKV;                   // 150994944  bf16 384*64*64
constexpr size_t OFF_TNB = OFF_TPB + 3145728;                 // 154140672
constexpr size_t OFF_VCT = OFF_TNB + 3145728;                 // 157286400  f32 vct[bh][d][m]
constexpr size_t OFF_OP  = OFF_VCT + 6291456;                 // 163577856  bf16 32768*768
constexpr size_t OFF_XB  = OFF_OP + SZ_QKV;                   // 213909504
constexpr size_t OFF_WQ  = OFF_XB + SZ_QKV;                   // 264241152
constexpr size_t OFF_WP  = OFF_WQ + 3538944;                  // 267780096
// end = 268075008 bytes (< previous 274 MB usage)

// ---- K0: f32 -> bf16 cast --------------------------------------------------
__global__ __launch_bounds__(256) void cast_kernel(const float* __restrict__ src,
                                                   unsigned short* __restrict__ dst, int n4) {
  int i = blockIdx.x * 256 + threadIdx.x;
  if (i >= n4) return;
  float4 v = reinterpret_cast<const float4*>(src)[i];
  ushort4 o;
  o.x = f2bf(v.x); o.y = f2bf(v.y); o.z = f2bf(v.z); o.w = f2bf(v.w);
  reinterpret_cast<ushort4*>(dst)[i] = o;
}

// ---- K1: qkv GEMM, M=32768 N=2304 K=768; q,k normal; v transposed ---------
__global__ __launch_bounds__(256) void gemm_qkv_kernel(const unsigned short* __restrict__ A,
    const unsigned short* __restrict__ Bm, unsigned short* __restrict__ q,
    unsigned short* __restrict__ k, unsigned short* __restrict__ vt) {
  __shared__ unsigned short As[128 * 40];
  __shared__ unsigned short Bs[128 * 40];
  const int t = threadIdx.x;
  const int lane = t & 63;
  const int w = t >> 6;
  const int wm = w >> 1, wn = w & 1;
  const int row0 = blockIdx.y * 128;
  const int col0 = blockIdx.x * 128;
  f32x4 acc[4][4];
#pragma unroll
  for (int i = 0; i < 4; ++i)
#pragma unroll
    for (int j = 0; j < 4; ++j) acc[i][j] = (f32x4){0.f, 0.f, 0.f, 0.f};
  const int mrow = lane & 15;
  const int kr = (lane >> 4) << 3;   // 0,8,16,24
  for (int k0 = 0; k0 < 768; k0 += 32) {
    __syncthreads();
    for (int L = t; L < 512; L += 256) {
      const int r = L >> 2, c8 = (L & 3) << 3;
      *reinterpret_cast<short8*>(As + r * 40 + c8) =
          *reinterpret_cast<const short8*>(A + (size_t)(row0 + r) * 768 + k0 + c8);
      *reinterpret_cast<short8*>(Bs + r * 40 + c8) =
          *reinterpret_cast<const short8*>(Bm + (size_t)(col0 + r) * 768 + k0 + c8);
    }
    __syncthreads();
    short8 af[4], bfv[4];
#pragma unroll
    for (int mt = 0; mt < 4; ++mt)
      af[mt] = *reinterpret_cast<const short8*>(As + (wm * 64 + mt * 16 + mrow) * 40 + kr);
#pragma unroll
    for (int nt = 0; nt < 4; ++nt)
      bfv[nt] = *reinterpret_cast<const short8*>(Bs + (wn * 64 + nt * 16 + mrow) * 40 + kr);
#pragma unroll
    for (int mt = 0; mt < 4; ++mt)
#pragma unroll
      for (int nt = 0; nt < 4; ++nt)
        acc[mt][nt] = __builtin_amdgcn_mfma_f32_16x16x32_bf16(af[mt], bfv[nt], acc[mt][nt], 0, 0, 0);
  }
  const int s_ = col0 / 768;   // 0..5 q, 6..11 k, 12..17 v (tiles never cross)
  if (s_ == 2) {
    // V: store transposed vt[((b*12+head)*64 + d)*1024 + n], 4 consecutive n packed
#pragma unroll
    for (int nt = 0; nt < 4; ++nt) {
      const int colin = wn * 64 + nt * 16 + mrow;
      const int head = ((col0 % 768) + colin) >> 6;
      const int d = colin & 63;
#pragma unroll
      for (int mt = 0; mt < 4; ++mt) {
        const int row = row0 + wm * 64 + mt * 16 + ((lane >> 4) << 2);
        const int b = row >> 10, n = row & 1023;
        ushort4 pk;
        pk.x = f2bf(acc[mt][nt][0]); pk.y = f2bf(acc[mt][nt][1]);
        pk.z = f2bf(acc[mt][nt][2]); pk.w = f2bf(acc[mt][nt][3]);
        *reinterpret_cast<ushort4*>(vt + ((((size_t)b * 12 + head) * 64 + d) << 10) + n) = pk;
      }
    }
  } else {
    unsigned short* dst = (s_ == 0) ? q : k;
#pragma unroll
    for (int nt = 0; nt < 4; ++nt) {
      const int colin = wn * 64 + nt * 16 + mrow;
      const int head = ((col0 % 768) + colin) >> 6;
      const int d = colin & 63;
#pragma unroll
      for (int mt = 0; mt < 4; ++mt) {
#pragma unroll
        for (int r = 0; r < 4; ++r) {
          const int row = row0 + wm * 64 + mt * 16 + ((lane >> 4) << 2) + r;
          const int b = row >> 10, n = row & 1023;
          dst[(((size_t)b * 12 + head) * 1024 + n) * 64 + d] = f2bf(acc[mt][nt][r]);
        }
      }
    }
  }
}

// ---- K2: conv3x3 depthwise + GELU + pool + gq -> t_pos/t_neg (bf16) -------
__global__ __launch_bounds__(256) void conv_pool_kernel(const unsigned short* __restrict__ qg,
    const float* __restrict__ conv_w, const float* __restrict__ Wpos,
    const float* __restrict__ Wneg, unsigned short* __restrict__ t_pos,
    unsigned short* __restrict__ t_neg) {
  const int bh = blockIdx.x;               // 0..383
  const unsigned short* qp = qg + (size_t)bh * 1024 * 64;
  __shared__ float pool_s[64][64];
  __shared__ float red[4][64];
  __shared__ float gq_s[64], ep_s[64], en_s[64];
  const int t = threadIdx.x;
  const int d = t & 63;
  { // gq = mean over n of raw q
    const int part = t >> 6;
    float s = 0.f;
    for (int i = 0; i < 256; ++i) s += bf2f(qp[(size_t)(part * 256 + i) * 64 + d]);
    red[part][d] = s;
  }
  __syncthreads();
  if (t < 64) gq_s[t] = (red[0][t] + red[1][t] + red[2][t] + red[3][t]) * (1.0f / 1024.0f);
  float cw[9];
#pragma unroll
  for (int j = 0; j < 9; ++j) cw[j] = conv_w[d * 9 + j];
  for (int i = 0; i < 16; ++i) {
    const int task = i * 256 + t;
    const int m = task >> 6;               // pooled token 0..63
    const int py = m >> 3, px = m & 7;
    float sum = 0.f;
    for (int iy = 0; iy < 4; ++iy) {
      const int y = py * 4 + iy;
      for (int ix = 0; ix < 4; ++ix) {
        const int x = px * 4 + ix;
        float acc = 0.f;
#pragma unroll
        for (int dy = -1; dy <= 1; ++dy) {
          const int yy = y + dy;
          if (yy < 0 || yy > 31) continue;
#pragma unroll
          for (int dx = -1; dx <= 1; ++dx) {
            const int xx = x + dx;
            if (xx < 0 || xx > 31) continue;
            acc += bf2f(qp[(size_t)(yy * 32 + xx) * 64 + d]) * cw[(dy + 1) * 3 + (dx + 1)];
          }
        }
        sum += 0.5f * acc * (1.0f + erff(acc * 0.70710678118654752440f));
      }
    }
    pool_s[m][d] = sum * (1.0f / 16.0f);
  }
  __syncthreads();
  if (t < 128) {
    const int d2 = t & 63;
    const float* Wm = (t < 64) ? Wpos : Wneg;
    float e = 0.f;
    for (int dd = 0; dd < 64; ++dd) e += gq_s[dd] * Wm[d2 * 64 + dd];
    (t < 64 ? ep_s : en_s)[d2] = e;
  }
  __syncthreads();
  for (int i = 0; i < 16; ++i) {
    const int task = i * 256 + t;
    const int m = task >> 6, dd = task & 63;
    const float base = pool_s[m][dd];
    t_pos[(size_t)bh * 4096 + task] = f2bf(base + ep_s[dd]);
    t_neg[(size_t)bh * 4096 + task] = f2bf(base + en_s[dd]);
  }
}

// ---- K3: stage-1 MFMA flash attention + contrast + rmsnorm ----------------
// block = (b,h); 4 waves; wave w owns t-token strip m = w*16..w*16+15.
// Swapped QK^T: S^T[n][m] = mfma32(K_frag, T_frag) -> lane: m = lane&15,
// n = tile*16 + 4*(lane>>4) + r.  P regs feed mfma16 A-frag directly (k=n).
__global__ __launch_bounds__(256) void stage1_kernel(const unsigned short* __restrict__ kg,
    const unsigned short* __restrict__ vtg, const unsigned short* __restrict__ tpb,
    const unsigned short* __restrict__ tnb, const float* __restrict__ lam1p,
    const float* __restrict__ norm1_w, float* __restrict__ vct) {
  const int bh = blockIdx.x;
  __shared__ unsigned short tp[64 * 72], tn[64 * 72];
  __shared__ unsigned short Ks[64 * 72], Vts[64 * 72];
  const int t = threadIdx.x;
  const int lane = t & 63;
  const int w = t >> 6;
  const int l = lane & 15, g = lane >> 4;
  for (int L = t; L < 512; L += 256) {
    const int r = L >> 3, c = (L & 7) << 3;
    *reinterpret_cast<short8*>(tp + r * 72 + c) =
        *reinterpret_cast<const short8*>(tpb + (size_t)bh * 4096 + r * 64 + c);
    *reinterpret_cast<short8*>(tn + r * 72 + c) =
        *reinterpret_cast<const short8*>(tnb + (size_t)bh * 4096 + r * 64 + c);
  }
  __syncthreads();
  short8 tf[2][2];   // [pass][khalf]  B-operand = T rows (cols of S^T)
#pragma unroll
  for (int h = 0; h < 2; ++h) {
    tf[0][h] = *reinterpret_cast<const short8*>(tp + (w * 16 + l) * 72 + h * 32 + g * 8);
    tf[1][h] = *reinterpret_cast<const short8*>(tn + (w * 16 + l) * 72 + h * 32 + g * 8);
  }
  float Mo[2] = {-1e30f, -1e30f}, Lo[2] = {0.f, 0.f};
  f32x4 acc[2][4];   // [pass][d-tile]; rows m = 4g+r, col d = dt*16+l
#pragma unroll
  for (int pp = 0; pp < 2; ++pp)
#pragma unroll
    for (int dt = 0; dt < 4; ++dt) acc[pp][dt] = (f32x4){0.f, 0.f, 0.f, 0.f};
  const size_t kbase = (size_t)bh * 65536;

  for (int n0 = 0; n0 < 1024; n0 += 64) {
    __syncthreads();
    for (int L = t; L < 512; L += 256) {
      const int r = L >> 3, c = (L & 7) << 3;
      *reinterpret_cast<short8*>(Ks + r * 72 + c) =
          *reinterpret_cast<const short8*>(kg + kbase + (size_t)(n0 + r) * 64 + c);
      // vt row r = d, cols n0+c..  (vt[bh][d][n])
      *reinterpret_cast<short8*>(Vts + r * 72 + c) =
          *reinterpret_cast<const short8*>(vtg + kbase + (size_t)r * 1024 + n0 + c);
    }
    __syncthreads();
    short8 kf[4][2];
#pragma unroll
    for (int tile = 0; tile < 4; ++tile)
#pragma unroll
      for (int h = 0; h < 2; ++h)
        kf[tile][h] = *reinterpret_cast<const short8*>(Ks + (tile * 16 + l) * 72 + h * 32 + g * 8);
    bf16x4 pf[2][4];
#pragma unroll
    for (int pp = 0; pp < 2; ++pp) {
      f32x4 s[4];
#pragma unroll
      for (int tile = 0; tile < 4; ++tile) {
        s[tile] = (f32x4){0.f, 0.f, 0.f, 0.f};
#pragma unroll
        for (int h = 0; h < 2; ++h)
          s[tile] = __builtin_amdgcn_mfma_f32_16x16x32_bf16(kf[tile][h], tf[pp][h], s[tile], 0, 0, 0);
      }
      float p[4][4];
      float tmax = -1e30f;
#pragma unroll
      for (int tile = 0; tile < 4; ++tile)
#pragma unroll
        for (int r = 0; r < 4; ++r) {
          const float v = s[tile][r] * 0.125f;
          p[tile][r] = v;
          tmax = fmaxf(tmax, v);
        }
      tmax = fmaxf(tmax, __shfl_xor(tmax, 16));
      tmax = fmaxf(tmax, __shfl_xor(tmax, 32));
      const float nm = fmaxf(Mo[pp], tmax);
      const float al = __expf(Mo[pp] - nm);
      Mo[pp] = nm;
      float ps = 0.f;
#pragma unroll
      for (int tile = 0; tile < 4; ++tile)
#pragma unroll
        for (int r = 0; r < 4; ++r) {
          const float e = __expf(p[tile][r] - nm);
          p[tile][r] = e;
          ps += e;
        }
      ps += __shfl_xor(ps, 16);
      ps += __shfl_xor(ps, 32);
      Lo[pp] = Lo[pp] * al + ps;
#pragma unroll
      for (int tile = 0; tile < 4; ++tile) {
        bf16x4 pk;
        pk[0] = (short)f2bf(p[tile][0]); pk[1] = (short)f2bf(p[tile][1]);
        pk[2] = (short)f2bf(p[tile][2]); pk[3] = (short)f2bf(p[tile][3]);
        pf[pp][tile] = pk;
      }
      float ar[4];
#pragma unroll
      for (int r = 0; r < 4; ++r) ar[r] = __shfl(al, 4 * g + r);
#pragma unroll
      for (int dt = 0; dt < 4; ++dt)
#pragma unroll
        for (int r = 0; r < 4; ++r) acc[pp][dt][r] *= ar[r];
    }
    // joint PV: vt frags shared by both passes
#pragma unroll
    for (int tile = 0; tile < 4; ++tile)
#pragma unroll
      for (int dt = 0; dt < 4; ++dt) {
        const bf16x4 vf = *reinterpret_cast<const bf16x4*>(Vts + (dt * 16 + l) * 72 + tile * 16 + g * 4);
        acc[0][dt] = __builtin_amdgcn_mfma_f32_16x16x16bf16_1k(pf[0][tile], vf, acc[0][dt], 0, 0, 0);
        acc[1][dt] = __builtin_amdgcn_mfma_f32_16x16x16bf16_1k(pf[1][tile], vf, acc[1][dt], 0, 0, 0);
      }
  }
  const float inv0 = 1.f / Lo[0], inv1 = 1.f / Lo[1];
  float i1r[4], i2r[4];
#pragma unroll
  for (int r = 0; r < 4; ++r) {
    i1r[r] = __shfl(inv0, 4 * g + r);
    i2r[r] = __shfl(inv1, 4 * g + r);
  }
  const float lam1 = lam1p[0];
  float od[4][4], ss[4] = {0.f, 0.f, 0.f, 0.f};
#pragma unroll
  for (int dt = 0; dt < 4; ++dt)
#pragma unroll
    for (int r = 0; r < 4; ++r) {
      const float v = acc[0][dt][r] * i1r[r] - lam1 * (acc[1][dt][r] * i2r[r]);
      od[dt][r] = v;
      ss[r] += v * v;
    }
#pragma unroll
  for (int r = 0; r < 4; ++r) {
    ss[r] += __shfl_xor(ss[r], 1);
    ss[r] += __shfl_xor(ss[r], 2);
    ss[r] += __shfl_xor(ss[r], 4);
    ss[r] += __shfl_xor(ss[r], 8);
  }
  float sc[4];
#pragma unroll
  for (int r = 0; r < 4; ++r) sc[r] = 0.5f / (sqrtf(ss[r]) * 0.125f + 1e-6f);
  const int mb = w * 16 + 4 * g;
#pragma unroll
  for (int dt = 0; dt < 4; ++dt) {
    const int dd = dt * 16 + l;
    const float nw = norm1_w[dd];
#pragma unroll
    for (int r = 0; r < 4; ++r)
      vct[(size_t)bh * 4096 + dd * 64 + mb + r] = od[dt][r] * sc[r] * nw;   // vct[bh][d][m]
  }
}

// ---- K4: stage-2 MFMA attention + rmsnorm -> out_patch bf16 ---------------
// block = (bh, 64-row q chunk); wave w owns q strip w*16..; kv = 64 tokens.
__global__ __launch_bounds__(256) void stage2_kernel(const unsigned short* __restrict__ qg,
    const unsigned short* __restrict__ tpb, const unsigned short* __restrict__ tnb,
    const float* __restrict__ vct, const float* __restrict__ lam2p,
    const float* __restrict__ norm2_w, unsigned short* __restrict__ opb) {
  const int bh = blockIdx.x;
  const int q0 = blockIdx.y * 64;
  __shared__ unsigned short tp[64 * 72], tn[64 * 72], Qs[64 * 72], Vc[64 * 72];
  const int t = threadIdx.x;
  const int lane = t & 63;
  const int w = t >> 6;
  const int l = lane & 15, g = lane >> 4;
  for (int L = t; L < 512; L += 256) {
    const int r = L >> 3, c = (L & 7) << 3;
    *reinterpret_cast<short8*>(tp + r * 72 + c) =
        *reinterpret_cast<const short8*>(tpb + (size_t)bh * 4096 + r * 64 + c);
    *reinterpret_cast<short8*>(tn + r * 72 + c) =
        *reinterpret_cast<const short8*>(tnb + (size_t)bh * 4096 + r * 64 + c);
    *reinterpret_cast<short8*>(Qs + r * 72 + c) =
        *reinterpret_cast<const short8*>(qg + (size_t)bh * 65536 + (size_t)(q0 + r) * 64 + c);
  }
  for (int L = t; L < 4096; L += 256) {
    const int dd = L >> 6, m = L & 63;
    Vc[dd * 72 + m] = f2bf(vct[(size_t)bh * 4096 + L]);   // Vc[d][m]
  }
  __syncthreads();
  short8 qf[2];
#pragma unroll
  for (int h = 0; h < 2; ++h)
    qf[h] = *reinterpret_cast<const short8*>(Qs + (w * 16 + l) * 72 + h * 32 + g * 8);
  bf16x4 vcf[4][4];
#pragma unroll
  for (int tile = 0; tile < 4; ++tile)
#pragma unroll
    for (int dt = 0; dt < 4; ++dt)
      vcf[tile][dt] = *reinterpret_cast<const bf16x4*>(Vc + (dt * 16 + l) * 72 + tile * 16 + g * 4);
  bf16x4 pf[2][4];
#pragma unroll
  for (int pp = 0; pp < 2; ++pp) {
    const unsigned short* tm = pp ? tn : tp;
    f32x4 s[4];
#pragma unroll
    for (int tile = 0; tile < 4; ++tile) {
      s[tile] = (f32x4){0.f, 0.f, 0.f, 0.f};
#pragma unroll
      for (int h = 0; h < 2; ++h) {
        const short8 tfb = *reinterpret_cast<const short8*>(tm + (tile * 16 + l) * 72 + h * 32 + g * 8);
        s[tile] = __builtin_amdgcn_mfma_f32_16x16x32_bf16(tfb, qf[h], s[tile], 0, 0, 0);
      }
    }
    float p[4][4];
    float lmax = -1e30f;
#pragma unroll
    for (int tile = 0; tile < 4; ++tile)
#pragma unroll
      for (int r = 0; r < 4; ++r) {
        const float v = s[tile][r] * 0.125f;
        p[tile][r] = v;
        lmax = fmaxf(lmax, v);
      }
    lmax = fmaxf(lmax, __shfl_xor(lmax, 16));
    lmax = fmaxf(lmax, __shfl_xor(lmax, 32));
    float ps = 0.f;
#pragma unroll
    for (int tile = 0; tile < 4; ++tile)
#pragma unroll
      for (int r = 0; r < 4; ++r) {
        const float e = __expf(p[tile][r] - lmax);
        p[tile][r] = e;
        ps += e;
      }
    ps += __shfl_xor(ps, 16);
    ps += __shfl_xor(ps, 32);
    const float inv = 1.f / ps;
#pragma unroll
    for (int tile = 0; tile < 4; ++tile) {
      bf16x4 pk;
      pk[0] = (short)f2bf(p[tile][0] * inv); pk[1] = (short)f2bf(p[tile][1] * inv);
      pk[2] = (short)f2bf(p[tile][2] * inv); pk[3] = (short)f2bf(p[tile][3] * inv);
      pf[pp][tile] = pk;
    }
  }
  f32x4 a1[4], a2[4];
#pragma unroll
  for (int dt = 0; dt < 4; ++dt) {
    a1[dt] = (f32x4){0.f, 0.f, 0.f, 0.f};
    a2[dt] = (f32x4){0.f, 0.f, 0.f, 0.f};
  }
#pragma unroll
  for (int tile = 0; tile < 4; ++tile)
#pragma unroll
    for (int dt = 0; dt < 4; ++dt) {
      a1[dt] = __builtin_amdgcn_mfma_f32_16x16x16bf16_1k(pf[0][tile], vcf[tile][dt], a1[dt], 0, 0, 0);
      a2[dt] = __builtin_amdgcn_mfma_f32_16x16x16bf16_1k(pf[1][tile], vcf[tile][dt], a2[dt], 0, 0, 0);
    }
  const float lam2 = lam2p[0];
  float od[4][4], ss[4] = {0.f, 0.f, 0.f, 0.f};
#pragma unroll
  for (int dt = 0; dt < 4; ++dt)
#pragma unroll
    for (int r = 0; r < 4; ++r) {
      const float v = a1[dt][r] - lam2 * a2[dt][r];
      od[dt][r] = v;
      ss[r] += v * v;
    }
#pragma unroll
  for (int r = 0; r < 4; ++r) {
    ss[r] += __shfl_xor(ss[r], 1);
    ss[r] += __shfl_xor(ss[r], 2);
    ss[r] += __shfl_xor(ss[r], 4);
    ss[r] += __shfl_xor(ss[r], 8);
  }
  float sc[4];
#pragma unroll
  for (int r = 0; r < 4; ++r) sc[r] = 0.5f / (sqrtf(ss[r]) * 0.125f + 1e-6f);
  const int b = bh / 12, head = bh % 12;
  const size_t ob = ((size_t)b * 1024 + q0 + w * 16 + 4 * g) * 768 + head * 64;
#pragma unroll
  for (int dt = 0; dt < 4; ++dt) {
    const float nw = norm2_w[dt * 16 + l];
#pragma unroll
    for (int r = 0; r < 4; ++r)
      opb[ob + (size_t)r * 768 + dt * 16 + l] = f2bf(od[dt][r] * sc[r] * nw);
  }
}

// ---- K5: projection GEMM, M=32768 N=768 K=768, +bias, f32 out -------------
__global__ __launch_bounds__(256) void gemm_proj_kernel(const unsigned short* __restrict__ A,
    const unsigned short* __restrict__ Bm, const float* __restrict__ bias,
    float* __restrict__ out) {
  __shared__ unsigned short As[128 * 40];
  __shared__ unsigned short Bs[128 * 40];
  const int t = threadIdx.x;
  const int lane = t & 63;
  const int w = t >> 6;
  const int wm = w >> 1, wn = w & 1;
  const int row0 = blockIdx.y * 128;
  const int col0 = blockIdx.x * 128;
  f32x4 acc[4][4];
#pragma unroll
  for (int i = 0; i < 4; ++i)
#pragma unroll
    for (int j = 0; j < 4; ++j) acc[i][j] = (f32x4){0.f, 0.f, 0.f, 0.f};
  const int mrow = lane & 15;
  const int kr = (lane >> 4) << 3;
  for (int k0 = 0; k0 < 768; k0 += 32) {
    __syncthreads();
    for (int L = t; L < 512; L += 256) {
      const int r = L >> 2, c8 = (L & 3) << 3;
      *reinterpret_cast<short8*>(As + r * 40 + c8) =
          *reinterpret_cast<const short8*>(A + (size_t)(row0 + r) * 768 + k0 + c8);
      *reinterpret_cast<short8*>(Bs + r * 40 + c8) =
          *reinterpret_cast<const short8*>(Bm + (size_t)(col0 + r) * 768 + k0 + c8);
    }
    __syncthreads();
    short8 af[4], bfv[4];
#pragma unroll
    for (int mt = 0; mt < 4; ++mt)
      af[mt] = *reinterpret_cast<const short8*>(As + (wm * 64 + mt * 16 + mrow) * 40 + kr);
#pragma unroll
    for (int nt = 0; nt < 4; ++nt)
      bfv[nt] = *reinterpret_cast<const short8*>(Bs + (wn * 64 + nt * 16 + mrow) * 40 + kr);
#pragma unroll
    for (int mt = 0; mt < 4; ++mt)
#pragma unroll
      for (int nt = 0; nt < 4; ++nt)
        acc[mt][nt] = __builtin_amdgcn_mfma_f32_16x16x32_bf16(af[mt], bfv[nt], acc[mt][nt], 0, 0, 0);
  }
#pragma unroll
  for (int nt = 0; nt < 4; ++nt) {
    const int col = col0 + wn * 64 + nt * 16 + mrow;
    const float bv = bias[col];
#pragma unroll
    for (int mt = 0; mt < 4; ++mt)
#pragma unroll
      for (int r = 0; r < 4; ++r) {
        const int row = row0 + wm * 64 + mt * 16 + ((lane >> 4) << 2) + r;
        out[(size_t)row * 768 + col] = acc[mt][nt][r] + bv;
      }
  }
}

// ---------------------------------------------------------------------------
extern "C" void kernel_launch(void* const* d_in, const int* in_sizes, int n_in,
                              void* d_out, int out_size, void* d_ws, size_t ws_size,
                              hipStream_t stream) {
  (void)in_sizes; (void)n_in; (void)out_size; (void)ws_size;
  const float* x       = (const float*)d_in[0];
  const float* Wqkv    = (const float*)d_in[1];
  const float* Wproj   = (const float*)d_in[2];
  const float* bproj   = (const float*)d_in[3];
  const float* Wpos    = (const float*)d_in[4];
  const float* Wneg    = (const float*)d_in[5];
  const float* conv_w  = (const float*)d_in[6];
  const float* lam1    = (const float*)d_in[7];
  const float* lam2    = (const float*)d_in[8];
  const float* norm1_w = (const float*)d_in[9];
  const float* norm2_w = (const float*)d_in[10];
  float* out = (float*)d_out;
  char* ws = (char*)d_ws;
  unsigned short* qb   = (unsigned short*)(ws + OFF_Q);
  unsigned short* kb   = (unsigned short*)(ws + OFF_K);
  unsigned short* vtb  = (unsigned short*)(ws + OFF_VT);
  unsigned short* tpbb = (unsigned short*)(ws + OFF_TPB);
  unsigned short* tnbb = (unsigned short*)(ws + OFF_TNB);
  float* vctb          = (float*)(ws + OFF_VCT);
  unsigned short* opb  = (unsigned short*)(ws + OFF_OP);
  unsigned short* xb   = (unsigned short*)(ws + OFF_XB);
  unsigned short* wqb  = (unsigned short*)(ws + OFF_WQ);
  unsigned short* wpb  = (unsigned short*)(ws + OFF_WP);

  cast_kernel<<<dim3(6291456 / 256), dim3(256), 0, stream>>>(x, xb, 6291456);
  cast_kernel<<<dim3(442368 / 256), dim3(256), 0, stream>>>(Wqkv, wqb, 442368);
  cast_kernel<<<dim3(147456 / 256), dim3(256), 0, stream>>>(Wproj, wpb, 147456);
  gemm_qkv_kernel<<<dim3(18, 256), dim3(256), 0, stream>>>(xb, wqb, qb, kb, vtb);
  conv_pool_kernel<<<dim3(384), dim3(256), 0, stream>>>(qb, conv_w, Wpos, Wneg, tpbb, tnbb);
  stage1_kernel<<<dim3(384), dim3(256), 0, stream>>>(kb, vtb, tpbb, tnbb, lam1, norm1_w, vctb);
  stage2_kernel<<<dim3(384, 16), dim3(256), 0, stream>>>(qb, tpbb, tnbb, vctb, lam2, norm2_w, opb);
  gemm_proj_kernel<<<dim3(6, 256), dim3(256), 0, stream>>>(opb, wpb, bproj, out);
}

// Round 3
// 593.735 us; speedup vs baseline: 11.4685x; 1.1134x over previous
//
#include <hip/hip_runtime.h>
#include <hip/hip_bf16.h>

// ---------------------------------------------------------------------------
// VisualContrastAttention on MI355X (gfx950)
// B=32, N=1024 (32x32), C=768, heads=12, hd=64, pool 8x8=64 tokens
// Pipeline:
//   K0  cast x/Wqkv/Wproj f32->bf16
//   K1  qkv GEMM (bf16 MFMA 16x16x32, global_load_lds staging, BK=64);
//       q,k stored [b,h,n,d]; V stored TRANSPOSED vt[b,h,d,n]
//   K2  depthwise conv3x3+GELU+avgpool + gq -> t_pos/t_neg (bf16)
//   K3  stage-1: swapped-QK^T MFMA flash (64 tok x 1024 kv, online softmax),
//       PV via mfma_16x16x16bf16_1k, writes v_contrast transposed vct[bh][d][m]
//   K4  stage-2: same structure (1024 q x 64 tok), out_patch bf16
//   K5  proj GEMM (bf16 MFMA, global_load_lds) + bias -> f32 d_out
// ---------------------------------------------------------------------------

typedef __attribute__((ext_vector_type(8))) short short8;
typedef __attribute__((ext_vector_type(4))) short bf16x4;
typedef __attribute__((ext_vector_type(4))) float f32x4;

#define DEV static __device__ __forceinline__

DEV unsigned short f2bf(float f) {
  unsigned int b; __builtin_memcpy(&b, &f, 4);
  unsigned int r = (b + 0x7FFFu + ((b >> 16) & 1u)) >> 16;
  return (unsigned short)r;
}
DEV float bf2f(unsigned short u) {
  unsigned int b = ((unsigned int)u) << 16;
  float f; __builtin_memcpy(&f, &b, 4);
  return f;
}

// async global(16B per lane) -> LDS(wave-uniform base + lane*16)
DEV void gload16(const unsigned short* g, unsigned short* l) {
  __builtin_amdgcn_global_load_lds(
      (const __attribute__((address_space(1))) unsigned int*)g,
      (__attribute__((address_space(3))) unsigned int*)l, 16, 0, 0);
}

// ---- workspace layout (bytes) ---------------------------------------------
constexpr size_t SZ_QKV = (size_t)32 * 12 * 1024 * 64 * 2;   // 50331648 bf16
constexpr size_t OFF_Q   = 0;
constexpr size_t OFF_K   = OFF_Q + SZ_QKV;                    //  50331648
constexpr size_t OFF_VT  = OFF_K + SZ_QKV;                    // 100663296  vt[bh][d][n] bf16
constexpr size_t OFF_TPB = OFF_VT + SZ_QKV;                   // 150994944  bf16 384*64*64
constexpr size_t OFF_TNB = OFF_TPB + 3145728;                 // 154140672
constexpr size_t OFF_VCT = OFF_TNB + 3145728;                 // 157286400  f32 vct[bh][d][m]
constexpr size_t OFF_OP  = OFF_VCT + 6291456;                 // 163577856  bf16 32768*768
constexpr size_t OFF_XB  = OFF_OP + SZ_QKV;                   // 213909504
constexpr size_t OFF_WQ  = OFF_XB + SZ_QKV;                   // 264241152
constexpr size_t OFF_WP  = OFF_WQ + 3538944;                  // 267780096

// ---- K0: f32 -> bf16 cast --------------------------------------------------
__global__ __launch_bounds__(256) void cast_kernel(const float* __restrict__ src,
                                                   unsigned short* __restrict__ dst, int n4) {
  int i = blockIdx.x * 256 + threadIdx.x;
  if (i >= n4) return;
  float4 v = reinterpret_cast<const float4*>(src)[i];
  ushort4 o;
  o.x = f2bf(v.x); o.y = f2bf(v.y); o.z = f2bf(v.z); o.w = f2bf(v.w);
  reinterpret_cast<ushort4*>(dst)[i] = o;
}

// ---- K1: qkv GEMM, M=32768 N=2304 K=768; q,k normal; v transposed ---------
// 128x128 tile, 4 waves (2x2), BK=64 as two [128][32] chunks, async staging.
__global__ __launch_bounds__(256) void gemm_qkv_kernel(const unsigned short* __restrict__ A,
    const unsigned short* __restrict__ Bm, unsigned short* __restrict__ q,
    unsigned short* __restrict__ k, unsigned short* __restrict__ vt) {
  __shared__ unsigned short As[2 * 128 * 32];   // [kc][row][32]
  __shared__ unsigned short Bs[2 * 128 * 32];
  const int t = threadIdx.x;
  const int lane = t & 63;
  const int w = t >> 6;
  const int wm = w >> 1, wn = w & 1;
  const int row0 = blockIdx.y * 128;
  const int col0 = blockIdx.x * 128;
  f32x4 acc[4][4];
#pragma unroll
  for (int i = 0; i < 4; ++i)
#pragma unroll
    for (int j = 0; j < 4; ++j) acc[i][j] = (f32x4){0.f, 0.f, 0.f, 0.f};
  const int l = lane & 15, g = lane >> 4;
  const int srow = lane >> 2, scol = (lane & 3) << 3;   // staging: 16 rows x 32 cols per 1KB slot
  for (int k0 = 0; k0 < 768; k0 += 64) {
    __syncthreads();
#pragma unroll
    for (int kc = 0; kc < 2; ++kc)
#pragma unroll
      for (int j = 0; j < 2; ++j) {
        const int qs = w * 2 + j;                       // wave slot 0..7
        const int r = qs * 16 + srow;
        const int cg = k0 + kc * 32 + scol;
        gload16(A + (size_t)(row0 + r) * 768 + cg, As + kc * 4096 + qs * 512);
        gload16(Bm + (size_t)(col0 + r) * 768 + cg, Bs + kc * 4096 + qs * 512);
      }
    __syncthreads();
#pragma unroll
    for (int kc = 0; kc < 2; ++kc) {
      short8 af[4], bfv[4];
#pragma unroll
      for (int mt = 0; mt < 4; ++mt)
        af[mt] = *reinterpret_cast<const short8*>(As + kc * 4096 + (wm * 64 + mt * 16 + l) * 32 + g * 8);
#pragma unroll
      for (int nt = 0; nt < 4; ++nt)
        bfv[nt] = *reinterpret_cast<const short8*>(Bs + kc * 4096 + (wn * 64 + nt * 16 + l) * 32 + g * 8);
#pragma unroll
      for (int mt = 0; mt < 4; ++mt)
#pragma unroll
        for (int nt = 0; nt < 4; ++nt)
          acc[mt][nt] = __builtin_amdgcn_mfma_f32_16x16x32_bf16(af[mt], bfv[nt], acc[mt][nt], 0, 0, 0);
    }
  }
  const int s_ = col0 / 768;   // 0 q, 1 k, 2 v (tiles never cross: 768%128==0)
  if (s_ == 2) {
#pragma unroll
    for (int nt = 0; nt < 4; ++nt) {
      const int colin = wn * 64 + nt * 16 + l;
      const int head = ((col0 % 768) + colin) >> 6;
      const int d = colin & 63;
#pragma unroll
      for (int mt = 0; mt < 4; ++mt) {
        const int row = row0 + wm * 64 + mt * 16 + (g << 2);
        const int b = row >> 10, n = row & 1023;
        ushort4 pk;
        pk.x = f2bf(acc[mt][nt][0]); pk.y = f2bf(acc[mt][nt][1]);
        pk.z = f2bf(acc[mt][nt][2]); pk.w = f2bf(acc[mt][nt][3]);
        *reinterpret_cast<ushort4*>(vt + ((((size_t)b * 12 + head) * 64 + d) << 10) + n) = pk;
      }
    }
  } else {
    unsigned short* dst = (s_ == 0) ? q : k;
#pragma unroll
    for (int nt = 0; nt < 4; ++nt) {
      const int colin = wn * 64 + nt * 16 + l;
      const int head = ((col0 % 768) + colin) >> 6;
      const int d = colin & 63;
#pragma unroll
      for (int mt = 0; mt < 4; ++mt) {
#pragma unroll
        for (int r = 0; r < 4; ++r) {
          const int row = row0 + wm * 64 + mt * 16 + (g << 2) + r;
          const int b = row >> 10, n = row & 1023;
          dst[(((size_t)b * 12 + head) * 1024 + n) * 64 + d] = f2bf(acc[mt][nt][r]);
        }
      }
    }
  }
}

// ---- K2: conv3x3 depthwise + GELU + pool + gq -> t_pos/t_neg (bf16) -------
__global__ __launch_bounds__(256) void conv_pool_kernel(const unsigned short* __restrict__ qg,
    const float* __restrict__ conv_w, const float* __restrict__ Wpos,
    const float* __restrict__ Wneg, unsigned short* __restrict__ t_pos,
    unsigned short* __restrict__ t_neg) {
  const int bh = blockIdx.x;               // 0..383
  const unsigned short* qp = qg + (size_t)bh * 1024 * 64;
  __shared__ float pool_s[64][64];
  __shared__ float red2[32][64];
  __shared__ float gq_s[64], ep_s[64], en_s[64];
  const int t = threadIdx.x;
  const int d = t & 63;
  { // gq = mean over n of raw q — vectorized short8 loads
    const int c8 = (t & 7) << 3;
    const int part = t >> 3;               // 0..31, 32 rows each
    float s[8] = {0.f, 0.f, 0.f, 0.f, 0.f, 0.f, 0.f, 0.f};
    for (int i = 0; i < 32; ++i) {
      const short8 v = *reinterpret_cast<const short8*>(qp + (size_t)(part * 32 + i) * 64 + c8);
#pragma unroll
      for (int j = 0; j < 8; ++j) s[j] += bf2f((unsigned short)v[j]);
    }
#pragma unroll
    for (int j = 0; j < 8; ++j) red2[part][c8 + j] = s[j];
  }
  __syncthreads();
  if (t < 64) {
    float s = 0.f;
    for (int p = 0; p < 32; ++p) s += red2[p][t];
    gq_s[t] = s * (1.0f / 1024.0f);
  }
  float cw[9];
#pragma unroll
  for (int j = 0; j < 9; ++j) cw[j] = conv_w[d * 9 + j];
  for (int i = 0; i < 16; ++i) {
    const int task = i * 256 + t;
    const int m = task >> 6;               // pooled token 0..63
    const int py = m >> 3, px = m & 7;
    float sum = 0.f;
    for (int iy = 0; iy < 4; ++iy) {
      const int y = py * 4 + iy;
      for (int ix = 0; ix < 4; ++ix) {
        const int x = px * 4 + ix;
        float acc = 0.f;
#pragma unroll
        for (int dy = -1; dy <= 1; ++dy) {
          const int yy = y + dy;
          if (yy < 0 || yy > 31) continue;
#pragma unroll
          for (int dx = -1; dx <= 1; ++dx) {
            const int xx = x + dx;
            if (xx < 0 || xx > 31) continue;
            acc += bf2f(qp[(size_t)(yy * 32 + xx) * 64 + d]) * cw[(dy + 1) * 3 + (dx + 1)];
          }
        }
        sum += 0.5f * acc * (1.0f + erff(acc * 0.70710678118654752440f));
      }
    }
    pool_s[m][d] = sum * (1.0f / 16.0f);
  }
  __syncthreads();
  if (t < 128) {
    const int d2 = t & 63;
    const float* Wm = (t < 64) ? Wpos : Wneg;
    float e = 0.f;
    for (int dd = 0; dd < 64; ++dd) e += gq_s[dd] * Wm[d2 * 64 + dd];
    (t < 64 ? ep_s : en_s)[d2] = e;
  }
  __syncthreads();
  for (int i = 0; i < 16; ++i) {
    const int task = i * 256 + t;
    const int m = task >> 6, dd = task & 63;
    const float base = pool_s[m][dd];
    t_pos[(size_t)bh * 4096 + task] = f2bf(base + ep_s[dd]);
    t_neg[(size_t)bh * 4096 + task] = f2bf(base + en_s[dd]);
  }
}

// ---- K3: stage-1 MFMA flash attention + contrast + rmsnorm ----------------
__global__ __launch_bounds__(256) void stage1_kernel(const unsigned short* __restrict__ kg,
    const unsigned short* __restrict__ vtg, const unsigned short* __restrict__ tpb,
    const unsigned short* __restrict__ tnb, const float* __restrict__ lam1p,
    const float* __restrict__ norm1_w, float* __restrict__ vct) {
  const int bh = blockIdx.x;
  __shared__ unsigned short tp[64 * 72], tn[64 * 72];
  __shared__ unsigned short Ks[64 * 72], Vts[64 * 72];
  const int t = threadIdx.x;
  const int lane = t & 63;
  const int w = t >> 6;
  const int l = lane & 15, g = lane >> 4;
  for (int L = t; L < 512; L += 256) {
    const int r = L >> 3, c = (L & 7) << 3;
    *reinterpret_cast<short8*>(tp + r * 72 + c) =
        *reinterpret_cast<const short8*>(tpb + (size_t)bh * 4096 + r * 64 + c);
    *reinterpret_cast<short8*>(tn + r * 72 + c) =
        *reinterpret_cast<const short8*>(tnb + (size_t)bh * 4096 + r * 64 + c);
  }
  __syncthreads();
  short8 tf[2][2];   // [pass][khalf]
#pragma unroll
  for (int h = 0; h < 2; ++h) {
    tf[0][h] = *reinterpret_cast<const short8*>(tp + (w * 16 + l) * 72 + h * 32 + g * 8);
    tf[1][h] = *reinterpret_cast<const short8*>(tn + (w * 16 + l) * 72 + h * 32 + g * 8);
  }
  float Mo[2] = {-1e30f, -1e30f}, Lo[2] = {0.f, 0.f};
  f32x4 acc[2][4];
#pragma unroll
  for (int pp = 0; pp < 2; ++pp)
#pragma unroll
    for (int dt = 0; dt < 4; ++dt) acc[pp][dt] = (f32x4){0.f, 0.f, 0.f, 0.f};
  const size_t kbase = (size_t)bh * 65536;

  for (int n0 = 0; n0 < 1024; n0 += 64) {
    __syncthreads();
    for (int L = t; L < 512; L += 256) {
      const int r = L >> 3, c = (L & 7) << 3;
      *reinterpret_cast<short8*>(Ks + r * 72 + c) =
          *reinterpret_cast<const short8*>(kg + kbase + (size_t)(n0 + r) * 64 + c);
      *reinterpret_cast<short8*>(Vts + r * 72 + c) =
          *reinterpret_cast<const short8*>(vtg + kbase + (size_t)r * 1024 + n0 + c);
    }
    __syncthreads();
    short8 kf[4][2];
#pragma unroll
    for (int tile = 0; tile < 4; ++tile)
#pragma unroll
      for (int h = 0; h < 2; ++h)
        kf[tile][h] = *reinterpret_cast<const short8*>(Ks + (tile * 16 + l) * 72 + h * 32 + g * 8);
    bf16x4 pf[2][4];
#pragma unroll
    for (int pp = 0; pp < 2; ++pp) {
      f32x4 s[4];
#pragma unroll
      for (int tile = 0; tile < 4; ++tile) {
        s[tile] = (f32x4){0.f, 0.f, 0.f, 0.f};
#pragma unroll
        for (int h = 0; h < 2; ++h)
          s[tile] = __builtin_amdgcn_mfma_f32_16x16x32_bf16(kf[tile][h], tf[pp][h], s[tile], 0, 0, 0);
      }
      float p[4][4];
      float tmax = -1e30f;
#pragma unroll
      for (int tile = 0; tile < 4; ++tile)
#pragma unroll
        for (int r = 0; r < 4; ++r) {
          const float v = s[tile][r] * 0.125f;
          p[tile][r] = v;
          tmax = fmaxf(tmax, v);
        }
      tmax = fmaxf(tmax, __shfl_xor(tmax, 16));
      tmax = fmaxf(tmax, __shfl_xor(tmax, 32));
      const float nm = fmaxf(Mo[pp], tmax);
      const float al = __expf(Mo[pp] - nm);
      Mo[pp] = nm;
      float ps = 0.f;
#pragma unroll
      for (int tile = 0; tile < 4; ++tile)
#pragma unroll
        for (int r = 0; r < 4; ++r) {
          const float e = __expf(p[tile][r] - nm);
          p[tile][r] = e;
          ps += e;
        }
      ps += __shfl_xor(ps, 16);
      ps += __shfl_xor(ps, 32);
      Lo[pp] = Lo[pp] * al + ps;
#pragma unroll
      for (int tile = 0; tile < 4; ++tile) {
        bf16x4 pk;
        pk[0] = (short)f2bf(p[tile][0]); pk[1] = (short)f2bf(p[tile][1]);
        pk[2] = (short)f2bf(p[tile][2]); pk[3] = (short)f2bf(p[tile][3]);
        pf[pp][tile] = pk;
      }
      float ar[4];
#pragma unroll
      for (int r = 0; r < 4; ++r) ar[r] = __shfl(al, 4 * g + r);
#pragma unroll
      for (int dt = 0; dt < 4; ++dt)
#pragma unroll
        for (int r = 0; r < 4; ++r) acc[pp][dt][r] *= ar[r];
    }
#pragma unroll
    for (int tile = 0; tile < 4; ++tile)
#pragma unroll
      for (int dt = 0; dt < 4; ++dt) {
        const bf16x4 vf = *reinterpret_cast<const bf16x4*>(Vts + (dt * 16 + l) * 72 + tile * 16 + g * 4);
        acc[0][dt] = __builtin_amdgcn_mfma_f32_16x16x16bf16_1k(pf[0][tile], vf, acc[0][dt], 0, 0, 0);
        acc[1][dt] = __builtin_amdgcn_mfma_f32_16x16x16bf16_1k(pf[1][tile], vf, acc[1][dt], 0, 0, 0);
      }
  }
  const float inv0 = 1.f / Lo[0], inv1 = 1.f / Lo[1];
  float i1r[4], i2r[4];
#pragma unroll
  for (int r = 0; r < 4; ++r) {
    i1r[r] = __shfl(inv0, 4 * g + r);
    i2r[r] = __shfl(inv1, 4 * g + r);
  }
  const float lam1 = lam1p[0];
  float od[4][4], ss[4] = {0.f, 0.f, 0.f, 0.f};
#pragma unroll
  for (int dt = 0; dt < 4; ++dt)
#pragma unroll
    for (int r = 0; r < 4; ++r) {
      const float v = acc[0][dt][r] * i1r[r] - lam1 * (acc[1][dt][r] * i2r[r]);
      od[dt][r] = v;
      ss[r] += v * v;
    }
#pragma unroll
  for (int r = 0; r < 4; ++r) {
    ss[r] += __shfl_xor(ss[r], 1);
    ss[r] += __shfl_xor(ss[r], 2);
    ss[r] += __shfl_xor(ss[r], 4);
    ss[r] += __shfl_xor(ss[r], 8);
  }
  float sc[4];
#pragma unroll
  for (int r = 0; r < 4; ++r) sc[r] = 0.5f / (sqrtf(ss[r]) * 0.125f + 1e-6f);
  const int mb = w * 16 + 4 * g;
#pragma unroll
  for (int dt = 0; dt < 4; ++dt) {
    const int dd = dt * 16 + l;
    const float nw = norm1_w[dd];
#pragma unroll
    for (int r = 0; r < 4; ++r)
      vct[(size_t)bh * 4096 + dd * 64 + mb + r] = od[dt][r] * sc[r] * nw;
  }
}

// ---- K4: stage-2 MFMA attention + rmsnorm -> out_patch bf16 ---------------
__global__ __launch_bounds__(256) void stage2_kernel(const unsigned short* __restrict__ qg,
    const unsigned short* __restrict__ tpb, const unsigned short* __restrict__ tnb,
    const float* __restrict__ vct, const float* __restrict__ lam2p,
    const float* __restrict__ norm2_w, unsigned short* __restrict__ opb) {
  const int bh = blockIdx.x;
  const int q0 = blockIdx.y * 64;
  __shared__ unsigned short tp[64 * 72], tn[64 * 72], Qs[64 * 72], Vc[64 * 72];
  const int t = threadIdx.x;
  const int lane = t & 63;
  const int w = t >> 6;
  const int l = lane & 15, g = lane >> 4;
  for (int L = t; L < 512; L += 256) {
    const int r = L >> 3, c = (L & 7) << 3;
    *reinterpret_cast<short8*>(tp + r * 72 + c) =
        *reinterpret_cast<const short8*>(tpb + (size_t)bh * 4096 + r * 64 + c);
    *reinterpret_cast<short8*>(tn + r * 72 + c) =
        *reinterpret_cast<const short8*>(tnb + (size_t)bh * 4096 + r * 64 + c);
    *reinterpret_cast<short8*>(Qs + r * 72 + c) =
        *reinterpret_cast<const short8*>(qg + (size_t)bh * 65536 + (size_t)(q0 + r) * 64 + c);
  }
  for (int L = t; L < 4096; L += 256) {
    const int dd = L >> 6, m = L & 63;
    Vc[dd * 72 + m] = f2bf(vct[(size_t)bh * 4096 + L]);
  }
  __syncthreads();
  short8 qf[2];
#pragma unroll
  for (int h = 0; h < 2; ++h)
    qf[h] = *reinterpret_cast<const short8*>(Qs + (w * 16 + l) * 72 + h * 32 + g * 8);
  bf16x4 vcf[4][4];
#pragma unroll
  for (int tile = 0; tile < 4; ++tile)
#pragma unroll
    for (int dt = 0; dt < 4; ++dt)
      vcf[tile][dt] = *reinterpret_cast<const bf16x4*>(Vc + (dt * 16 + l) * 72 + tile * 16 + g * 4);
  bf16x4 pf[2][4];
#pragma unroll
  for (int pp = 0; pp < 2; ++pp) {
    const unsigned short* tm = pp ? tn : tp;
    f32x4 s[4];
#pragma unroll
    for (int tile = 0; tile < 4; ++tile) {
      s[tile] = (f32x4){0.f, 0.f, 0.f, 0.f};
#pragma unroll
      for (int h = 0; h < 2; ++h) {
        const short8 tfb = *reinterpret_cast<const short8*>(tm + (tile * 16 + l) * 72 + h * 32 + g * 8);
        s[tile] = __builtin_amdgcn_mfma_f32_16x16x32_bf16(tfb, qf[h], s[tile], 0, 0, 0);
      }
    }
    float p[4][4];
    float lmax = -1e30f;
#pragma unroll
    for (int tile = 0; tile < 4; ++tile)
#pragma unroll
      for (int r = 0; r < 4; ++r) {
        const float v = s[tile][r] * 0.125f;
        p[tile][r] = v;
        lmax = fmaxf(lmax, v);
      }
    lmax = fmaxf(lmax, __shfl_xor(lmax, 16));
    lmax = fmaxf(lmax, __shfl_xor(lmax, 32));
    float ps = 0.f;
#pragma unroll
    for (int tile = 0; tile < 4; ++tile)
#pragma unroll
      for (int r = 0; r < 4; ++r) {
        const float e = __expf(p[tile][r] - lmax);
        p[tile][r] = e;
        ps += e;
      }
    ps += __shfl_xor(ps, 16);
    ps += __shfl_xor(ps, 32);
    const float inv = 1.f / ps;
#pragma unroll
    for (int tile = 0; tile < 4; ++tile) {
      bf16x4 pk;
      pk[0] = (short)f2bf(p[tile][0] * inv); pk[1] = (short)f2bf(p[tile][1] * inv);
      pk[2] = (short)f2bf(p[tile][2] * inv); pk[3] = (short)f2bf(p[tile][3] * inv);
      pf[pp][tile] = pk;
    }
  }
  f32x4 a1[4], a2[4];
#pragma unroll
  for (int dt = 0; dt < 4; ++dt) {
    a1[dt] = (f32x4){0.f, 0.f, 0.f, 0.f};
    a2[dt] = (f32x4){0.f, 0.f, 0.f, 0.f};
  }
#pragma unroll
  for (int tile = 0; tile < 4; ++tile)
#pragma unroll
    for (int dt = 0; dt < 4; ++dt) {
      a1[dt] = __builtin_amdgcn_mfma_f32_16x16x16bf16_1k(pf[0][tile], vcf[tile][dt], a1[dt], 0, 0, 0);
      a2[dt] = __builtin_amdgcn_mfma_f32_16x16x16bf16_1k(pf[1][tile], vcf[tile][dt], a2[dt], 0, 0, 0);
    }
  const float lam2 = lam2p[0];
  float od[4][4], ss[4] = {0.f, 0.f, 0.f, 0.f};
#pragma unroll
  for (int dt = 0; dt < 4; ++dt)
#pragma unroll
    for (int r = 0; r < 4; ++r) {
      const float v = a1[dt][r] - lam2 * a2[dt][r];
      od[dt][r] = v;
      ss[r] += v * v;
    }
#pragma unroll
  for (int r = 0; r < 4; ++r) {
    ss[r] += __shfl_xor(ss[r], 1);
    ss[r] += __shfl_xor(ss[r], 2);
    ss[r] += __shfl_xor(ss[r], 4);
    ss[r] += __shfl_xor(ss[r], 8);
  }
  float sc[4];
#pragma unroll
  for (int r = 0; r < 4; ++r) sc[r] = 0.5f / (sqrtf(ss[r]) * 0.125f + 1e-6f);
  const int b = bh / 12, head = bh % 12;
  const size_t ob = ((size_t)b * 1024 + q0 + w * 16 + 4 * g) * 768 + head * 64;
#pragma unroll
  for (int dt = 0; dt < 4; ++dt) {
    const float nw = norm2_w[dt * 16 + l];
#pragma unroll
    for (int r = 0; r < 4; ++r)
      opb[ob + (size_t)r * 768 + dt * 16 + l] = f2bf(od[dt][r] * sc[r] * nw);
  }
}

// ---- K5: projection GEMM, M=32768 N=768 K=768, +bias, f32 out -------------
__global__ __launch_bounds__(256) void gemm_proj_kernel(const unsigned short* __restrict__ A,
    const unsigned short* __restrict__ Bm, const float* __restrict__ bias,
    float* __restrict__ out) {
  __shared__ unsigned short As[2 * 128 * 32];
  __shared__ unsigned short Bs[2 * 128 * 32];
  const int t = threadIdx.x;
  const int lane = t & 63;
  const int w = t >> 6;
  const int wm = w >> 1, wn = w & 1;
  const int row0 = blockIdx.y * 128;
  const int col0 = blockIdx.x * 128;
  f32x4 acc[4][4];
#pragma unroll
  for (int i = 0; i < 4; ++i)
#pragma unroll
    for (int j = 0; j < 4; ++j) acc[i][j] = (f32x4){0.f, 0.f, 0.f, 0.f};
  const int l = lane & 15, g = lane >> 4;
  const int srow = lane >> 2, scol = (lane & 3) << 3;
  for (int k0 = 0; k0 < 768; k0 += 64) {
    __syncthreads();
#pragma unroll
    for (int kc = 0; kc < 2; ++kc)
#pragma unroll
      for (int j = 0; j < 2; ++j) {
        const int qs = w * 2 + j;
        const int r = qs * 16 + srow;
        const int cg = k0 + kc * 32 + scol;
        gload16(A + (size_t)(row0 + r) * 768 + cg, As + kc * 4096 + qs * 512);
        gload16(Bm + (size_t)(col0 + r) * 768 + cg, Bs + kc * 4096 + qs * 512);
      }
    __syncthreads();
#pragma unroll
    for (int kc = 0; kc < 2; ++kc) {
      short8 af[4], bfv[4];
#pragma unroll
      for (int mt = 0; mt < 4; ++mt)
        af[mt] = *reinterpret_cast<const short8*>(As + kc * 4096 + (wm * 64 + mt * 16 + l) * 32 + g * 8);
#pragma unroll
      for (int nt = 0; nt < 4; ++nt)
        bfv[nt] = *reinterpret_cast<const short8*>(Bs + kc * 4096 + (wn * 64 + nt * 16 + l) * 32 + g * 8);
#pragma unroll
      for (int mt = 0; mt < 4; ++mt)
#pragma unroll
        for (int nt = 0; nt < 4; ++nt)
          acc[mt][nt] = __builtin_amdgcn_mfma_f32_16x16x32_bf16(af[mt], bfv[nt], acc[mt][nt], 0, 0, 0);
    }
  }
#pragma unroll
  for (int nt = 0; nt < 4; ++nt) {
    const int col = col0 + wn * 64 + nt * 16 + l;
    const float bv = bias[col];
#pragma unroll
    for (int mt = 0; mt < 4; ++mt)
#pragma unroll
      for (int r = 0; r < 4; ++r) {
        const int row = row0 + wm * 64 + mt * 16 + (g << 2) + r;
        out[(size_t)row * 768 + col] = acc[mt][nt][r] + bv;
      }
  }
}

// ---------------------------------------------------------------------------
extern "C" void kernel_launch(void* const* d_in, const int* in_sizes, int n_in,
                              void* d_out, int out_size, void* d_ws, size_t ws_size,
                              hipStream_t stream) {
  (void)in_sizes; (void)n_in; (void)out_size; (void)ws_size;
  const float* x       = (const float*)d_in[0];
  const float* Wqkv    = (const float*)d_in[1];
  const float* Wproj   = (const float*)d_in[2];
  const float* bproj   = (const float*)d_in[3];
  const float* Wpos    = (const float*)d_in[4];
  const float* Wneg    = (const float*)d_in[5];
  const float* conv_w  = (const float*)d_in[6];
  const float* lam1    = (const float*)d_in[7];
  const float* lam2    = (const float*)d_in[8];
  const float* norm1_w = (const float*)d_in[9];
  const float* norm2_w = (const float*)d_in[10];
  float* out = (float*)d_out;
  char* ws = (char*)d_ws;
  unsigned short* qb   = (unsigned short*)(ws + OFF_Q);
  unsigned short* kb   = (unsigned short*)(ws + OFF_K);
  unsigned short* vtb  = (unsigned short*)(ws + OFF_VT);
  unsigned short* tpbb = (unsigned short*)(ws + OFF_TPB);
  unsigned short* tnbb = (unsigned short*)(ws + OFF_TNB);
  float* vctb          = (float*)(ws + OFF_VCT);
  unsigned short* opb  = (unsigned short*)(ws + OFF_OP);
  unsigned short* xb   = (unsigned short*)(ws + OFF_XB);
  unsigned short* wqb  = (unsigned short*)(ws + OFF_WQ);
  unsigned short* wpb  = (unsigned short*)(ws + OFF_WP);

  cast_kernel<<<dim3(6291456 / 256), dim3(256), 0, stream>>>(x, xb, 6291456);
  cast_kernel<<<dim3(442368 / 256), dim3(256), 0, stream>>>(Wqkv, wqb, 442368);
  cast_kernel<<<dim3(147456 / 256), dim3(256), 0, stream>>>(Wproj, wpb, 147456);
  gemm_qkv_kernel<<<dim3(18, 256), dim3(256), 0, stream>>>(xb, wqb, qb, kb, vtb);
  conv_pool_kernel<<<dim3(384), dim3(256), 0, stream>>>(qb, conv_w, Wpos, Wneg, tpbb, tnbb);
  stage1_kernel<<<dim3(384), dim3(256), 0, stream>>>(kb, vtb, tpbb, tnbb, lam1, norm1_w, vctb);
  stage2_kernel<<<dim3(384, 16), dim3(256), 0, stream>>>(qb, tpbb, tnbb, vctb, lam2, norm2_w, opb);
  gemm_proj_kernel<<<dim3(6, 256), dim3(256), 0, stream>>>(opb, wpb, bproj, out);
}

// Round 4
// 453.910 us; speedup vs baseline: 15.0013x; 1.3080x over previous
//
#include <hip/hip_runtime.h>
#include <hip/hip_bf16.h>

// ---------------------------------------------------------------------------
// VisualContrastAttention on MI355X (gfx950)
// B=32, N=1024 (32x32), C=768, heads=12, hd=64, pool 8x8=64 tokens
// Pipeline:
//   K0  cast x/Wqkv/Wproj f32->bf16
//   K1  qkv GEMM (bf16 MFMA 16x16x32, global_load_lds staging, BK=64);
//       q,k stored [b,h,n,d]; V stored TRANSPOSED vt[b,h,d,n]
//   K2a gq reduction + Wpos/Wneg embeddings -> ep/en[384][64] f32
//   K2b depthwise conv3x3+GELU+avgpool (vectorized short8, grid x4)
//       -> t_pos/t_neg (bf16)
//   K3  stage-1: swapped-QK^T MFMA flash (64 tok x 1024 kv, online softmax),
//       PV via mfma_16x16x16bf16_1k, writes v_contrast transposed vct[bh][d][m]
//   K4  stage-2: same structure (1024 q x 64 tok), out_patch bf16
//   K5  proj GEMM (bf16 MFMA, global_load_lds) + bias -> f32 d_out
// ---------------------------------------------------------------------------

typedef __attribute__((ext_vector_type(8))) short short8;
typedef __attribute__((ext_vector_type(4))) short bf16x4;
typedef __attribute__((ext_vector_type(4))) float f32x4;

#define DEV static __device__ __forceinline__

DEV unsigned short f2bf(float f) {
  unsigned int b; __builtin_memcpy(&b, &f, 4);
  unsigned int r = (b + 0x7FFFu + ((b >> 16) & 1u)) >> 16;
  return (unsigned short)r;
}
DEV float bf2f(unsigned short u) {
  unsigned int b = ((unsigned int)u) << 16;
  float f; __builtin_memcpy(&f, &b, 4);
  return f;
}

// async global(16B per lane) -> LDS(wave-uniform base + lane*16)
DEV void gload16(const unsigned short* g, unsigned short* l) {
  __builtin_amdgcn_global_load_lds(
      (const __attribute__((address_space(1))) unsigned int*)g,
      (__attribute__((address_space(3))) unsigned int*)l, 16, 0, 0);
}

// ---- workspace layout (bytes) ---------------------------------------------
constexpr size_t SZ_QKV = (size_t)32 * 12 * 1024 * 64 * 2;   // 50331648 bf16
constexpr size_t OFF_Q   = 0;
constexpr size_t OFF_K   = OFF_Q + SZ_QKV;                    //  50331648
constexpr size_t OFF_VT  = OFF_K + SZ_QKV;                    // 100663296  vt[bh][d][n] bf16
constexpr size_t OFF_TPB = OFF_VT + SZ_QKV;                   // 150994944  bf16 384*64*64
constexpr size_t OFF_TNB = OFF_TPB + 3145728;                 // 154140672
constexpr size_t OFF_VCT = OFF_TNB + 3145728;                 // 157286400  f32 vct[bh][d][m]
constexpr size_t OFF_OP  = OFF_VCT + 6291456;                 // 163577856  bf16 32768*768
constexpr size_t OFF_XB  = OFF_OP + SZ_QKV;                   // 213909504
constexpr size_t OFF_WQ  = OFF_XB + SZ_QKV;                   // 264241152
constexpr size_t OFF_WP  = OFF_WQ + 3538944;                  // 267780096
constexpr size_t OFF_EP  = OFF_WP + 1179648;                  // 268959744  f32 384*64
constexpr size_t OFF_EN  = OFF_EP + 98304;                    // 269058048

// ---- K0: f32 -> bf16 cast --------------------------------------------------
__global__ __launch_bounds__(256) void cast_kernel(const float* __restrict__ src,
                                                   unsigned short* __restrict__ dst, int n4) {
  int i = blockIdx.x * 256 + threadIdx.x;
  if (i >= n4) return;
  float4 v = reinterpret_cast<const float4*>(src)[i];
  ushort4 o;
  o.x = f2bf(v.x); o.y = f2bf(v.y); o.z = f2bf(v.z); o.w = f2bf(v.w);
  reinterpret_cast<ushort4*>(dst)[i] = o;
}

// ---- K1: qkv GEMM, M=32768 N=2304 K=768; q,k normal; v transposed ---------
__global__ __launch_bounds__(256) void gemm_qkv_kernel(const unsigned short* __restrict__ A,
    const unsigned short* __restrict__ Bm, unsigned short* __restrict__ q,
    unsigned short* __restrict__ k, unsigned short* __restrict__ vt) {
  __shared__ unsigned short As[2 * 128 * 32];   // [kc][row][32]
  __shared__ unsigned short Bs[2 * 128 * 32];
  const int t = threadIdx.x;
  const int lane = t & 63;
  const int w = t >> 6;
  const int wm = w >> 1, wn = w & 1;
  const int row0 = blockIdx.y * 128;
  const int col0 = blockIdx.x * 128;
  f32x4 acc[4][4];
#pragma unroll
  for (int i = 0; i < 4; ++i)
#pragma unroll
    for (int j = 0; j < 4; ++j) acc[i][j] = (f32x4){0.f, 0.f, 0.f, 0.f};
  const int l = lane & 15, g = lane >> 4;
  const int srow = lane >> 2, scol = (lane & 3) << 3;
  for (int k0 = 0; k0 < 768; k0 += 64) {
    __syncthreads();
#pragma unroll
    for (int kc = 0; kc < 2; ++kc)
#pragma unroll
      for (int j = 0; j < 2; ++j) {
        const int qs = w * 2 + j;
        const int r = qs * 16 + srow;
        const int cg = k0 + kc * 32 + scol;
        gload16(A + (size_t)(row0 + r) * 768 + cg, As + kc * 4096 + qs * 512);
        gload16(Bm + (size_t)(col0 + r) * 768 + cg, Bs + kc * 4096 + qs * 512);
      }
    __syncthreads();
#pragma unroll
    for (int kc = 0; kc < 2; ++kc) {
      short8 af[4], bfv[4];
#pragma unroll
      for (int mt = 0; mt < 4; ++mt)
        af[mt] = *reinterpret_cast<const short8*>(As + kc * 4096 + (wm * 64 + mt * 16 + l) * 32 + g * 8);
#pragma unroll
      for (int nt = 0; nt < 4; ++nt)
        bfv[nt] = *reinterpret_cast<const short8*>(Bs + kc * 4096 + (wn * 64 + nt * 16 + l) * 32 + g * 8);
#pragma unroll
      for (int mt = 0; mt < 4; ++mt)
#pragma unroll
        for (int nt = 0; nt < 4; ++nt)
          acc[mt][nt] = __builtin_amdgcn_mfma_f32_16x16x32_bf16(af[mt], bfv[nt], acc[mt][nt], 0, 0, 0);
    }
  }
  const int s_ = col0 / 768;
  if (s_ == 2) {
#pragma unroll
    for (int nt = 0; nt < 4; ++nt) {
      const int colin = wn * 64 + nt * 16 + l;
      const int head = ((col0 % 768) + colin) >> 6;
      const int d = colin & 63;
#pragma unroll
      for (int mt = 0; mt < 4; ++mt) {
        const int row = row0 + wm * 64 + mt * 16 + (g << 2);
        const int b = row >> 10, n = row & 1023;
        ushort4 pk;
        pk.x = f2bf(acc[mt][nt][0]); pk.y = f2bf(acc[mt][nt][1]);
        pk.z = f2bf(acc[mt][nt][2]); pk.w = f2bf(acc[mt][nt][3]);
        *reinterpret_cast<ushort4*>(vt + ((((size_t)b * 12 + head) * 64 + d) << 10) + n) = pk;
      }
    }
  } else {
    unsigned short* dst = (s_ == 0) ? q : k;
#pragma unroll
    for (int nt = 0; nt < 4; ++nt) {
      const int colin = wn * 64 + nt * 16 + l;
      const int head = ((col0 % 768) + colin) >> 6;
      const int d = colin & 63;
#pragma unroll
      for (int mt = 0; mt < 4; ++mt) {
#pragma unroll
        for (int r = 0; r < 4; ++r) {
          const int row = row0 + wm * 64 + mt * 16 + (g << 2) + r;
          const int b = row >> 10, n = row & 1023;
          dst[(((size_t)b * 12 + head) * 1024 + n) * 64 + d] = f2bf(acc[mt][nt][r]);
        }
      }
    }
  }
}

// ---- K2a: gq reduction + e+/e- embeddings ---------------------------------
__global__ __launch_bounds__(256) void gq_embed_kernel(const unsigned short* __restrict__ qg,
    const float* __restrict__ Wpos, const float* __restrict__ Wneg,
    float* __restrict__ ep, float* __restrict__ en) {
  const int bh = blockIdx.x;               // 0..383
  const unsigned short* qp = qg + (size_t)bh * 65536;
  __shared__ float red2[32][64];
  __shared__ float gq_s[64];
  const int t = threadIdx.x;
  const int c8 = (t & 7) << 3;
  const int part = t >> 3;                 // 0..31
  float s[8] = {0.f, 0.f, 0.f, 0.f, 0.f, 0.f, 0.f, 0.f};
  for (int i = 0; i < 32; ++i) {
    const short8 v = *reinterpret_cast<const short8*>(qp + (size_t)(part * 32 + i) * 64 + c8);
#pragma unroll
    for (int j = 0; j < 8; ++j) s[j] += bf2f((unsigned short)v[j]);
  }
#pragma unroll
  for (int j = 0; j < 8; ++j) red2[part][c8 + j] = s[j];
  __syncthreads();
  if (t < 64) {
    float s2 = 0.f;
    for (int p = 0; p < 32; ++p) s2 += red2[p][t];
    gq_s[t] = s2 * (1.0f / 1024.0f);
  }
  __syncthreads();
  if (t < 128) {
    const int d2 = t & 63;
    const float* Wm = (t < 64) ? Wpos : Wneg;
    float e = 0.f;
    for (int dd = 0; dd < 64; ++dd) e += gq_s[dd] * Wm[d2 * 64 + dd];
    (t < 64 ? ep : en)[bh * 64 + d2] = e;
  }
}

// ---- K2b: conv3x3 depthwise + GELU + 4x4 mean pool -> t_pos/t_neg ---------
// grid (384, 4): block covers 8 y-rows (2 pooled rows). thread = (x=t>>3,
// 8-ch group dg=t&7). Window reduce via shfl_xor over the 4 x of a window.
__global__ __launch_bounds__(256) void conv_pool_kernel(const unsigned short* __restrict__ qg,
    const float* __restrict__ conv_w, const float* __restrict__ ep,
    const float* __restrict__ en, unsigned short* __restrict__ t_pos,
    unsigned short* __restrict__ t_neg) {
  const int bh = blockIdx.x;
  const int quad = blockIdx.y;             // y rows quad*8 .. quad*8+7
  const unsigned short* qp = qg + (size_t)bh * 65536;
  __shared__ float pool_s[16][64];
  const int t = threadIdx.x;
  const int dg = t & 7, sp = t >> 3;       // sp = x position 0..31
  const int d0 = dg << 3;
  float cw[3][3][8];
#pragma unroll
  for (int ky = 0; ky < 3; ++ky)
#pragma unroll
    for (int kx = 0; kx < 3; ++kx)
#pragma unroll
      for (int j = 0; j < 8; ++j)
        cw[ky][kx][j] = conv_w[(d0 + j) * 9 + ky * 3 + kx];
#pragma unroll
  for (int pyl = 0; pyl < 2; ++pyl) {
    float win[8] = {0.f, 0.f, 0.f, 0.f, 0.f, 0.f, 0.f, 0.f};
#pragma unroll
    for (int iy = 0; iy < 4; ++iy) {
      const int y = quad * 8 + pyl * 4 + iy;
      float a[8] = {0.f, 0.f, 0.f, 0.f, 0.f, 0.f, 0.f, 0.f};
#pragma unroll
      for (int ky = 0; ky < 3; ++ky) {
        const int yy = y + ky - 1;
        if (yy < 0 || yy > 31) continue;
#pragma unroll
        for (int kx = 0; kx < 3; ++kx) {
          const int xx = sp + kx - 1;
          if (xx < 0 || xx > 31) continue;
          const short8 v = *reinterpret_cast<const short8*>(qp + (size_t)(yy * 32 + xx) * 64 + d0);
#pragma unroll
          for (int j = 0; j < 8; ++j) a[j] += bf2f((unsigned short)v[j]) * cw[ky][kx][j];
        }
      }
#pragma unroll
      for (int j = 0; j < 8; ++j)
        win[j] += 0.5f * a[j] * (1.0f + erff(a[j] * 0.70710678118654752440f));
    }
    // reduce over the 4 x-positions of the pooled window (lane bits 3,4)
#pragma unroll
    for (int j = 0; j < 8; ++j) {
      win[j] += __shfl_xor(win[j], 8);
      win[j] += __shfl_xor(win[j], 16);
    }
    if ((sp & 3) == 0) {
      const int px = sp >> 2;
#pragma unroll
      for (int j = 0; j < 8; ++j) pool_s[pyl * 8 + px][d0 + j] = win[j];
    }
  }
  __syncthreads();
#pragma unroll
  for (int i = 0; i < 4; ++i) {
    const int idx = i * 256 + t;           // 0..1023
    const int m = idx >> 6, dd = idx & 63;
    const int mg = quad * 16 + m;
    const float base = pool_s[m][dd] * (1.0f / 16.0f);
    t_pos[(size_t)bh * 4096 + mg * 64 + dd] = f2bf(base + ep[bh * 64 + dd]);
    t_neg[(size_t)bh * 4096 + mg * 64 + dd] = f2bf(base + en[bh * 64 + dd]);
  }
}

// ---- K3: stage-1 MFMA flash attention + contrast + rmsnorm ----------------
__global__ __launch_bounds__(256) void stage1_kernel(const unsigned short* __restrict__ kg,
    const unsigned short* __restrict__ vtg, const unsigned short* __restrict__ tpb,
    const unsigned short* __restrict__ tnb, const float* __restrict__ lam1p,
    const float* __restrict__ norm1_w, float* __restrict__ vct) {
  const int bh = blockIdx.x;
  __shared__ unsigned short tp[64 * 72], tn[64 * 72];
  __shared__ unsigned short Ks[64 * 72], Vts[64 * 72];
  const int t = threadIdx.x;
  const int lane = t & 63;
  const int w = t >> 6;
  const int l = lane & 15, g = lane >> 4;
  for (int L = t; L < 512; L += 256) {
    const int r = L >> 3, c = (L & 7) << 3;
    *reinterpret_cast<short8*>(tp + r * 72 + c) =
        *reinterpret_cast<const short8*>(tpb + (size_t)bh * 4096 + r * 64 + c);
    *reinterpret_cast<short8*>(tn + r * 72 + c) =
        *reinterpret_cast<const short8*>(tnb + (size_t)bh * 4096 + r * 64 + c);
  }
  __syncthreads();
  short8 tf[2][2];
#pragma unroll
  for (int h = 0; h < 2; ++h) {
    tf[0][h] = *reinterpret_cast<const short8*>(tp + (w * 16 + l) * 72 + h * 32 + g * 8);
    tf[1][h] = *reinterpret_cast<const short8*>(tn + (w * 16 + l) * 72 + h * 32 + g * 8);
  }
  float Mo[2] = {-1e30f, -1e30f}, Lo[2] = {0.f, 0.f};
  f32x4 acc[2][4];
#pragma unroll
  for (int pp = 0; pp < 2; ++pp)
#pragma unroll
    for (int dt = 0; dt < 4; ++dt) acc[pp][dt] = (f32x4){0.f, 0.f, 0.f, 0.f};
  const size_t kbase = (size_t)bh * 65536;

  for (int n0 = 0; n0 < 1024; n0 += 64) {
    __syncthreads();
    for (int L = t; L < 512; L += 256) {
      const int r = L >> 3, c = (L & 7) << 3;
      *reinterpret_cast<short8*>(Ks + r * 72 + c) =
          *reinterpret_cast<const short8*>(kg + kbase + (size_t)(n0 + r) * 64 + c);
      *reinterpret_cast<short8*>(Vts + r * 72 + c) =
          *reinterpret_cast<const short8*>(vtg + kbase + (size_t)r * 1024 + n0 + c);
    }
    __syncthreads();
    short8 kf[4][2];
#pragma unroll
    for (int tile = 0; tile < 4; ++tile)
#pragma unroll
      for (int h = 0; h < 2; ++h)
        kf[tile][h] = *reinterpret_cast<const short8*>(Ks + (tile * 16 + l) * 72 + h * 32 + g * 8);
    bf16x4 pf[2][4];
#pragma unroll
    for (int pp = 0; pp < 2; ++pp) {
      f32x4 s[4];
#pragma unroll
      for (int tile = 0; tile < 4; ++tile) {
        s[tile] = (f32x4){0.f, 0.f, 0.f, 0.f};
#pragma unroll
        for (int h = 0; h < 2; ++h)
          s[tile] = __builtin_amdgcn_mfma_f32_16x16x32_bf16(kf[tile][h], tf[pp][h], s[tile], 0, 0, 0);
      }
      float p[4][4];
      float tmax = -1e30f;
#pragma unroll
      for (int tile = 0; tile < 4; ++tile)
#pragma unroll
        for (int r = 0; r < 4; ++r) {
          const float v = s[tile][r] * 0.125f;
          p[tile][r] = v;
          tmax = fmaxf(tmax, v);
        }
      tmax = fmaxf(tmax, __shfl_xor(tmax, 16));
      tmax = fmaxf(tmax, __shfl_xor(tmax, 32));
      const float nm = fmaxf(Mo[pp], tmax);
      const float al = __expf(Mo[pp] - nm);
      Mo[pp] = nm;
      float ps = 0.f;
#pragma unroll
      for (int tile = 0; tile < 4; ++tile)
#pragma unroll
        for (int r = 0; r < 4; ++r) {
          const float e = __expf(p[tile][r] - nm);
          p[tile][r] = e;
          ps += e;
        }
      ps += __shfl_xor(ps, 16);
      ps += __shfl_xor(ps, 32);
      Lo[pp] = Lo[pp] * al + ps;
#pragma unroll
      for (int tile = 0; tile < 4; ++tile) {
        bf16x4 pk;
        pk[0] = (short)f2bf(p[tile][0]); pk[1] = (short)f2bf(p[tile][1]);
        pk[2] = (short)f2bf(p[tile][2]); pk[3] = (short)f2bf(p[tile][3]);
        pf[pp][tile] = pk;
      }
      float ar[4];
#pragma unroll
      for (int r = 0; r < 4; ++r) ar[r] = __shfl(al, 4 * g + r);
#pragma unroll
      for (int dt = 0; dt < 4; ++dt)
#pragma unroll
        for (int r = 0; r < 4; ++r) acc[pp][dt][r] *= ar[r];
    }
#pragma unroll
    for (int tile = 0; tile < 4; ++tile)
#pragma unroll
      for (int dt = 0; dt < 4; ++dt) {
        const bf16x4 vf = *reinterpret_cast<const bf16x4*>(Vts + (dt * 16 + l) * 72 + tile * 16 + g * 4);
        acc[0][dt] = __builtin_amdgcn_mfma_f32_16x16x16bf16_1k(pf[0][tile], vf, acc[0][dt], 0, 0, 0);
        acc[1][dt] = __builtin_amdgcn_mfma_f32_16x16x16bf16_1k(pf[1][tile], vf, acc[1][dt], 0, 0, 0);
      }
  }
  const float inv0 = 1.f / Lo[0], inv1 = 1.f / Lo[1];
  float i1r[4], i2r[4];
#pragma unroll
  for (int r = 0; r < 4; ++r) {
    i1r[r] = __shfl(inv0, 4 * g + r);
    i2r[r] = __shfl(inv1, 4 * g + r);
  }
  const float lam1 = lam1p[0];
  float od[4][4], ss[4] = {0.f, 0.f, 0.f, 0.f};
#pragma unroll
  for (int dt = 0; dt < 4; ++dt)
#pragma unroll
    for (int r = 0; r < 4; ++r) {
      const float v = acc[0][dt][r] * i1r[r] - lam1 * (acc[1][dt][r] * i2r[r]);
      od[dt][r] = v;
      ss[r] += v * v;
    }
#pragma unroll
  for (int r = 0; r < 4; ++r) {
    ss[r] += __shfl_xor(ss[r], 1);
    ss[r] += __shfl_xor(ss[r], 2);
    ss[r] += __shfl_xor(ss[r], 4);
    ss[r] += __shfl_xor(ss[r], 8);
  }
  float sc[4];
#pragma unroll
  for (int r = 0; r < 4; ++r) sc[r] = 0.5f / (sqrtf(ss[r]) * 0.125f + 1e-6f);
  const int mb = w * 16 + 4 * g;
#pragma unroll
  for (int dt = 0; dt < 4; ++dt) {
    const int dd = dt * 16 + l;
    const float nw = norm1_w[dd];
#pragma unroll
    for (int r = 0; r < 4; ++r)
      vct[(size_t)bh * 4096 + dd * 64 + mb + r] = od[dt][r] * sc[r] * nw;
  }
}

// ---- K4: stage-2 MFMA attention + rmsnorm -> out_patch bf16 ---------------
__global__ __launch_bounds__(256) void stage2_kernel(const unsigned short* __restrict__ qg,
    const unsigned short* __restrict__ tpb, const unsigned short* __restrict__ tnb,
    const float* __restrict__ vct, const float* __restrict__ lam2p,
    const float* __restrict__ norm2_w, unsigned short* __restrict__ opb) {
  const int bh = blockIdx.x;
  const int q0 = blockIdx.y * 64;
  __shared__ unsigned short tp[64 * 72], tn[64 * 72], Qs[64 * 72], Vc[64 * 72];
  const int t = threadIdx.x;
  const int lane = t & 63;
  const int w = t >> 6;
  const int l = lane & 15, g = lane >> 4;
  for (int L = t; L < 512; L += 256) {
    const int r = L >> 3, c = (L & 7) << 3;
    *reinterpret_cast<short8*>(tp + r * 72 + c) =
        *reinterpret_cast<const short8*>(tpb + (size_t)bh * 4096 + r * 64 + c);
    *reinterpret_cast<short8*>(tn + r * 72 + c) =
        *reinterpret_cast<const short8*>(tnb + (size_t)bh * 4096 + r * 64 + c);
    *reinterpret_cast<short8*>(Qs + r * 72 + c) =
        *reinterpret_cast<const short8*>(qg + (size_t)bh * 65536 + (size_t)(q0 + r) * 64 + c);
  }
  for (int L = t; L < 4096; L += 256) {
    const int dd = L >> 6, m = L & 63;
    Vc[dd * 72 + m] = f2bf(vct[(size_t)bh * 4096 + L]);
  }
  __syncthreads();
  short8 qf[2];
#pragma unroll
  for (int h = 0; h < 2; ++h)
    qf[h] = *reinterpret_cast<const short8*>(Qs + (w * 16 + l) * 72 + h * 32 + g * 8);
  bf16x4 vcf[4][4];
#pragma unroll
  for (int tile = 0; tile < 4; ++tile)
#pragma unroll
    for (int dt = 0; dt < 4; ++dt)
      vcf[tile][dt] = *reinterpret_cast<const bf16x4*>(Vc + (dt * 16 + l) * 72 + tile * 16 + g * 4);
  bf16x4 pf[2][4];
#pragma unroll
  for (int pp = 0; pp < 2; ++pp) {
    const unsigned short* tm = pp ? tn : tp;
    f32x4 s[4];
#pragma unroll
    for (int tile = 0; tile < 4; ++tile) {
      s[tile] = (f32x4){0.f, 0.f, 0.f, 0.f};
#pragma unroll
      for (int h = 0; h < 2; ++h) {
        const short8 tfb = *reinterpret_cast<const short8*>(tm + (tile * 16 + l) * 72 + h * 32 + g * 8);
        s[tile] = __builtin_amdgcn_mfma_f32_16x16x32_bf16(tfb, qf[h], s[tile], 0, 0, 0);
      }
    }
    float p[4][4];
    float lmax = -1e30f;
#pragma unroll
    for (int tile = 0; tile < 4; ++tile)
#pragma unroll
      for (int r = 0; r < 4; ++r) {
        const float v = s[tile][r] * 0.125f;
        p[tile][r] = v;
        lmax = fmaxf(lmax, v);
      }
    lmax = fmaxf(lmax, __shfl_xor(lmax, 16));
    lmax = fmaxf(lmax, __shfl_xor(lmax, 32));
    float ps = 0.f;
#pragma unroll
    for (int tile = 0; tile < 4; ++tile)
#pragma unroll
      for (int r = 0; r < 4; ++r) {
        const float e = __expf(p[tile][r] - lmax);
        p[tile][r] = e;
        ps += e;
      }
    ps += __shfl_xor(ps, 16);
    ps += __shfl_xor(ps, 32);
    const float inv = 1.f / ps;
#pragma unroll
    for (int tile = 0; tile < 4; ++tile) {
      bf16x4 pk;
      pk[0] = (short)f2bf(p[tile][0] * inv); pk[1] = (short)f2bf(p[tile][1] * inv);
      pk[2] = (short)f2bf(p[tile][2] * inv); pk[3] = (short)f2bf(p[tile][3] * inv);
      pf[pp][tile] = pk;
    }
  }
  f32x4 a1[4], a2[4];
#pragma unroll
  for (int dt = 0; dt < 4; ++dt) {
    a1[dt] = (f32x4){0.f, 0.f, 0.f, 0.f};
    a2[dt] = (f32x4){0.f, 0.f, 0.f, 0.f};
  }
#pragma unroll
  for (int tile = 0; tile < 4; ++tile)
#pragma unroll
    for (int dt = 0; dt < 4; ++dt) {
      a1[dt] = __builtin_amdgcn_mfma_f32_16x16x16bf16_1k(pf[0][tile], vcf[tile][dt], a1[dt], 0, 0, 0);
      a2[dt] = __builtin_amdgcn_mfma_f32_16x16x16bf16_1k(pf[1][tile], vcf[tile][dt], a2[dt], 0, 0, 0);
    }
  const float lam2 = lam2p[0];
  float od[4][4], ss[4] = {0.f, 0.f, 0.f, 0.f};
#pragma unroll
  for (int dt = 0; dt < 4; ++dt)
#pragma unroll
    for (int r = 0; r < 4; ++r) {
      const float v = a1[dt][r] - lam2 * a2[dt][r];
      od[dt][r] = v;
      ss[r] += v * v;
    }
#pragma unroll
  for (int r = 0; r < 4; ++r) {
    ss[r] += __shfl_xor(ss[r], 1);
    ss[r] += __shfl_xor(ss[r], 2);
    ss[r] += __shfl_xor(ss[r], 4);
    ss[r] += __shfl_xor(ss[r], 8);
  }
  float sc[4];
#pragma unroll
  for (int r = 0; r < 4; ++r) sc[r] = 0.5f / (sqrtf(ss[r]) * 0.125f + 1e-6f);
  const int b = bh / 12, head = bh % 12;
  const size_t ob = ((size_t)b * 1024 + q0 + w * 16 + 4 * g) * 768 + head * 64;
#pragma unroll
  for (int dt = 0; dt < 4; ++dt) {
    const float nw = norm2_w[dt * 16 + l];
#pragma unroll
    for (int r = 0; r < 4; ++r)
      opb[ob + (size_t)r * 768 + dt * 16 + l] = f2bf(od[dt][r] * sc[r] * nw);
  }
}

// ---- K5: projection GEMM, M=32768 N=768 K=768, +bias, f32 out -------------
__global__ __launch_bounds__(256) void gemm_proj_kernel(const unsigned short* __restrict__ A,
    const unsigned short* __restrict__ Bm, const float* __restrict__ bias,
    float* __restrict__ out) {
  __shared__ unsigned short As[2 * 128 * 32];
  __shared__ unsigned short Bs[2 * 128 * 32];
  const int t = threadIdx.x;
  const int lane = t & 63;
  const int w = t >> 6;
  const int wm = w >> 1, wn = w & 1;
  const int row0 = blockIdx.y * 128;
  const int col0 = blockIdx.x * 128;
  f32x4 acc[4][4];
#pragma unroll
  for (int i = 0; i < 4; ++i)
#pragma unroll
    for (int j = 0; j < 4; ++j) acc[i][j] = (f32x4){0.f, 0.f, 0.f, 0.f};
  const int l = lane & 15, g = lane >> 4;
  const int srow = lane >> 2, scol = (lane & 3) << 3;
  for (int k0 = 0; k0 < 768; k0 += 64) {
    __syncthreads();
#pragma unroll
    for (int kc = 0; kc < 2; ++kc)
#pragma unroll
      for (int j = 0; j < 2; ++j) {
        const int qs = w * 2 + j;
        const int r = qs * 16 + srow;
        const int cg = k0 + kc * 32 + scol;
        gload16(A + (size_t)(row0 + r) * 768 + cg, As + kc * 4096 + qs * 512);
        gload16(Bm + (size_t)(col0 + r) * 768 + cg, Bs + kc * 4096 + qs * 512);
      }
    __syncthreads();
#pragma unroll
    for (int kc = 0; kc < 2; ++kc) {
      short8 af[4], bfv[4];
#pragma unroll
      for (int mt = 0; mt < 4; ++mt)
        af[mt] = *reinterpret_cast<const short8*>(As + kc * 4096 + (wm * 64 + mt * 16 + l) * 32 + g * 8);
#pragma unroll
      for (int nt = 0; nt < 4; ++nt)
        bfv[nt] = *reinterpret_cast<const short8*>(Bs + kc * 4096 + (wn * 64 + nt * 16 + l) * 32 + g * 8);
#pragma unroll
      for (int mt = 0; mt < 4; ++mt)
#pragma unroll
        for (int nt = 0; nt < 4; ++nt)
          acc[mt][nt] = __builtin_amdgcn_mfma_f32_16x16x32_bf16(af[mt], bfv[nt], acc[mt][nt], 0, 0, 0);
    }
  }
#pragma unroll
  for (int nt = 0; nt < 4; ++nt) {
    const int col = col0 + wn * 64 + nt * 16 + l;
    const float bv = bias[col];
#pragma unroll
    for (int mt = 0; mt < 4; ++mt)
#pragma unroll
      for (int r = 0; r < 4; ++r) {
        const int row = row0 + wm * 64 + mt * 16 + (g << 2) + r;
        out[(size_t)row * 768 + col] = acc[mt][nt][r] + bv;
      }
  }
}

// ---------------------------------------------------------------------------
extern "C" void kernel_launch(void* const* d_in, const int* in_sizes, int n_in,
                              void* d_out, int out_size, void* d_ws, size_t ws_size,
                              hipStream_t stream) {
  (void)in_sizes; (void)n_in; (void)out_size; (void)ws_size;
  const float* x       = (const float*)d_in[0];
  const float* Wqkv    = (const float*)d_in[1];
  const float* Wproj   = (const float*)d_in[2];
  const float* bproj   = (const float*)d_in[3];
  const float* Wpos    = (const float*)d_in[4];
  const float* Wneg    = (const float*)d_in[5];
  const float* conv_w  = (const float*)d_in[6];
  const float* lam1    = (const float*)d_in[7];
  const float* lam2    = (const float*)d_in[8];
  const float* norm1_w = (const float*)d_in[9];
  const float* norm2_w = (const float*)d_in[10];
  float* out = (float*)d_out;
  char* ws = (char*)d_ws;
  unsigned short* qb   = (unsigned short*)(ws + OFF_Q);
  unsigned short* kb   = (unsigned short*)(ws + OFF_K);
  unsigned short* vtb  = (unsigned short*)(ws + OFF_VT);
  unsigned short* tpbb = (unsigned short*)(ws + OFF_TPB);
  unsigned short* tnbb = (unsigned short*)(ws + OFF_TNB);
  float* vctb          = (float*)(ws + OFF_VCT);
  unsigned short* opb  = (unsigned short*)(ws + OFF_OP);
  unsigned short* xb   = (unsigned short*)(ws + OFF_XB);
  unsigned short* wqb  = (unsigned short*)(ws + OFF_WQ);
  unsigned short* wpb  = (unsigned short*)(ws + OFF_WP);
  float* epb           = (float*)(ws + OFF_EP);
  float* enb           = (float*)(ws + OFF_EN);

  cast_kernel<<<dim3(6291456 / 256), dim3(256), 0, stream>>>(x, xb, 6291456);
  cast_kernel<<<dim3(442368 / 256), dim3(256), 0, stream>>>(Wqkv, wqb, 442368);
  cast_kernel<<<dim3(147456 / 256), dim3(256), 0, stream>>>(Wproj, wpb, 147456);
  gemm_qkv_kernel<<<dim3(18, 256), dim3(256), 0, stream>>>(xb, wqb, qb, kb, vtb);
  gq_embed_kernel<<<dim3(384), dim3(256), 0, stream>>>(qb, Wpos, Wneg, epb, enb);
  conv_pool_kernel<<<dim3(384, 4), dim3(256), 0, stream>>>(qb, conv_w, epb, enb, tpbb, tnbb);
  stage1_kernel<<<dim3(384), dim3(256), 0, stream>>>(kb, vtb, tpbb, tnbb, lam1, norm1_w, vctb);
  stage2_kernel<<<dim3(384, 16), dim3(256), 0, stream>>>(qb, tpbb, tnbb, vctb, lam2, norm2_w, opb);
  gemm_proj_kernel<<<dim3(6, 256), dim3(256), 0, stream>>>(opb, wpb, bproj, out);
}